// Round 3
// baseline (895.648 us; speedup 1.0000x reference)
//
#include <hip/hip_runtime.h>
#include <hip/hip_bf16.h>

typedef __bf16 bf16;
typedef __attribute__((ext_vector_type(8))) __bf16 bf16x8;
typedef __attribute__((ext_vector_type(4))) __bf16 bf16x4;
typedef __attribute__((ext_vector_type(2))) __bf16 bf16x2;
typedef __attribute__((ext_vector_type(4))) float f32x4;

constexpr int N_NODES   = 100000;
constexpr int N_PAD     = 100032;   // multiple of 64 (GEMM block tile)
constexpr int D         = 128;
constexpr int D_FF      = 256;
constexpr int N_CLASSES = 26;
constexpr int N_GRAPHS  = 512;
constexpr int R         = 8;        // histogram replicas per node

__device__ inline float2 bf2f(unsigned u) {
    float lo = __uint_as_float(u << 16);
    float hi = __uint_as_float(u & 0xffff0000u);
    return make_float2(lo, hi);
}

// ---------------- graph preprocessing ----------------

// zero the replicated counters + starts sentinels
__global__ void init_kernel(int* counts8, int* starts, int n8) {
    int i = blockIdx.x * 256 + threadIdx.x;
    if (i < n8) counts8[i] = 0;
    if (i <= N_GRAPHS) starts[i] = N_NODES;
}

// replicated histogram: replica chosen by block -> concurrent blocks hit
// different counters within a node's 32B group (8x less line contention)
__global__ void hist_kernel(const int* __restrict__ edst, int* counts8,
                            int* __restrict__ eoff, int e) {
    int i = blockIdx.x * 256 + threadIdx.x;
    int r = blockIdx.x & (R - 1);
    if (i < e) eoff[i] = atomicAdd(&counts8[edst[i] * R + r], 1);
}

// per node: total count, exclusive prefix over replicas, dinv
__global__ void sum_kernel(const int* __restrict__ counts8, int* __restrict__ base8,
                           int* __restrict__ counts, float* __restrict__ dinv, int n) {
    int i = blockIdx.x * 256 + threadIdx.x;
    if (i >= n) return;
    int run = 0;
#pragma unroll
    for (int r = 0; r < R; ++r) {
        base8[i * R + r] = run;
        run += counts8[i * R + r];
    }
    counts[i] = run;
    dinv[i] = 1.0f / sqrtf((float)(run + 1));  // +1 = self-loop
}

// 3-phase exclusive scan of counts -> rowptr
__global__ __launch_bounds__(256) void scan1(const int* __restrict__ counts,
                                             int* rowptr, int* bsum, int n) {
    __shared__ int sd[256];
    int i = blockIdx.x * 256 + threadIdx.x;
    int v = (i < n) ? counts[i] : 0;
    sd[threadIdx.x] = v; __syncthreads();
    for (int off = 1; off < 256; off <<= 1) {
        int t = (threadIdx.x >= off) ? sd[threadIdx.x - off] : 0;
        __syncthreads();
        sd[threadIdx.x] += t;
        __syncthreads();
    }
    if (i < n) rowptr[i + 1] = sd[threadIdx.x];
    if (threadIdx.x == 255) bsum[blockIdx.x] = sd[255];
}

__global__ __launch_bounds__(512) void scan2(const int* __restrict__ bsum,
                                             int* boff, int nb) {
    __shared__ int sd[512];
    int t = threadIdx.x;
    int v = (t < nb) ? bsum[t] : 0;
    sd[t] = v; __syncthreads();
    for (int off = 1; off < 512; off <<= 1) {
        int x = (t >= off) ? sd[t - off] : 0;
        __syncthreads();
        sd[t] += x;
        __syncthreads();
    }
    if (t < nb) boff[t] = sd[t] - v;  // exclusive
}

__global__ void scan3(int* rowptr, const int* __restrict__ boff, int n) {
    int i = blockIdx.x * 256 + threadIdx.x;
    if (i < n) rowptr[i + 1] += boff[blockIdx.x];
    if (i == 0) rowptr[0] = 0;
}

// single scattered 4B write per edge
__global__ void fill_edges(const int* __restrict__ esrc, const int* __restrict__ edst,
                           const int* __restrict__ eoff, const int* __restrict__ rowptr,
                           const int* __restrict__ base8, int* __restrict__ csrc, int e) {
    int i = blockIdx.x * 256 + threadIdx.x;
    if (i >= e) return;
    int r = (i >> 8) & (R - 1);            // same replica hist_kernel used
    int d = edst[i];
    csrc[rowptr[d] + base8[d * R + r] + eoff[i]] = esrc[i];
}

__global__ void find_starts(const int* __restrict__ batch, int* starts, int n) {
    int i = blockIdx.x * 256 + threadIdx.x;
    if (i >= n) return;
    int b = batch[i];
    if (i == 0 || batch[i - 1] != b) atomicMin(&starts[b], i);
}

__global__ void fix_starts(int* starts) {
    if (blockIdx.x == 0 && threadIdx.x == 0) {
        for (int g = N_GRAPHS - 1; g >= 0; --g)
            if (starts[g] > starts[g + 1]) starts[g] = starts[g + 1];
    }
}

// ---------------- dense compute ----------------

__global__ void cast4_kernel(const float* __restrict__ src, bf16* __restrict__ dst,
                             int nvalid, int ntotal) {
    int i = (blockIdx.x * 256 + threadIdx.x) * 4;
    if (i >= ntotal) return;
    float4 v = make_float4(0.f, 0.f, 0.f, 0.f);
    if (i < nvalid) v = *(const float4*)(src + i);
    bf16x4 o = { (bf16)v.x, (bf16)v.y, (bf16)v.z, (bf16)v.w };
    *(bf16x4*)(dst + i) = o;
}

__global__ void castWT_kernel(const float* __restrict__ W, bf16* __restrict__ WT) {
    int n = blockIdx.x, k = threadIdx.x;
    WT[n * D + k] = (bf16)W[k * D + n];
}

// C[Mpad x 128] = A[Mpad x 128] @ W[128 x 128], bf16 in/out, no LDS.
__global__ __launch_bounds__(256) void gemm_kernel(const bf16* __restrict__ A,
                                                   const bf16* __restrict__ WT,
                                                   bf16* __restrict__ C) {
    int wave = threadIdx.x >> 6;
    int lane = threadIdx.x & 63;
    int m16  = lane & 15;
    int quad = lane >> 4;
    int row0 = blockIdx.x * 64 + wave * 16;

    bf16x8 a[4];
    const bf16* arow = A + (row0 + m16) * D + quad * 8;
#pragma unroll
    for (int kt = 0; kt < 4; ++kt)
        a[kt] = *(const bf16x8*)(arow + kt * 32);

#pragma unroll
    for (int nt = 0; nt < 8; ++nt) {
        f32x4 acc = {0.f, 0.f, 0.f, 0.f};
        const bf16* brow = WT + (nt * 16 + m16) * D + quad * 8;
#pragma unroll
        for (int kt = 0; kt < 4; ++kt) {
            bf16x8 b = *(const bf16x8*)(brow + kt * 32);
            acc = __builtin_amdgcn_mfma_f32_16x16x32_bf16(a[kt], b, acc, 0, 0, 0);
        }
#pragma unroll
        for (int r = 0; r < 4; ++r)
            C[(row0 + quad * 4 + r) * D + nt * 16 + m16] = (bf16)acc[r];
    }
}

// out[v][:] = relu( dinv[v]^2*h[v] + sum_e dinv[src]*dinv[v]*h[src] + bias )
// 4 waves/block, one node per wave; lane covers dims {2*lane, 2*lane+1}
__global__ __launch_bounds__(256) void spmm_kernel(const bf16* __restrict__ h,
                                                   const int* __restrict__ rowptr,
                                                   const int* __restrict__ csrc,
                                                   const float* __restrict__ dinv,
                                                   const float* __restrict__ bias,
                                                   bf16* __restrict__ out, int n) {
    int v = blockIdx.x * 4 + (threadIdx.x >> 6);
    if (v >= n) return;
    int lane = threadIdx.x & 63;
    int s = rowptr[v], e = rowptr[v + 1];
    float dv = dinv[v];

    unsigned su = *(const unsigned*)(h + v * D + lane * 2);
    float2 sf = bf2f(su);
    float accx = dv * dv * sf.x;
    float accy = dv * dv * sf.y;

    for (int j0 = s; j0 < e; j0 += 64) {
        int nn = min(64, e - j0);
        int idx = 0; float w = 0.f;
        if (j0 + lane < e) { idx = csrc[j0 + lane]; w = dinv[idx] * dv; }
        int t = 0;
        for (; t + 8 <= nn; t += 8) {
            int s0 = __shfl(idx, t),     s1 = __shfl(idx, t + 1);
            int s2 = __shfl(idx, t + 2), s3 = __shfl(idx, t + 3);
            int s4 = __shfl(idx, t + 4), s5 = __shfl(idx, t + 5);
            int s6 = __shfl(idx, t + 6), s7 = __shfl(idx, t + 7);
            unsigned u0 = *(const unsigned*)(h + s0 * D + lane * 2);
            unsigned u1 = *(const unsigned*)(h + s1 * D + lane * 2);
            unsigned u2 = *(const unsigned*)(h + s2 * D + lane * 2);
            unsigned u3 = *(const unsigned*)(h + s3 * D + lane * 2);
            unsigned u4 = *(const unsigned*)(h + s4 * D + lane * 2);
            unsigned u5 = *(const unsigned*)(h + s5 * D + lane * 2);
            unsigned u6 = *(const unsigned*)(h + s6 * D + lane * 2);
            unsigned u7 = *(const unsigned*)(h + s7 * D + lane * 2);
            float w0 = __shfl(w, t),     w1 = __shfl(w, t + 1);
            float w2 = __shfl(w, t + 2), w3 = __shfl(w, t + 3);
            float w4 = __shfl(w, t + 4), w5 = __shfl(w, t + 5);
            float w6 = __shfl(w, t + 6), w7 = __shfl(w, t + 7);
            float2 f0 = bf2f(u0), f1 = bf2f(u1), f2 = bf2f(u2), f3 = bf2f(u3);
            float2 f4 = bf2f(u4), f5 = bf2f(u5), f6 = bf2f(u6), f7 = bf2f(u7);
            accx = fmaf(w0, f0.x, accx); accy = fmaf(w0, f0.y, accy);
            accx = fmaf(w1, f1.x, accx); accy = fmaf(w1, f1.y, accy);
            accx = fmaf(w2, f2.x, accx); accy = fmaf(w2, f2.y, accy);
            accx = fmaf(w3, f3.x, accx); accy = fmaf(w3, f3.y, accy);
            accx = fmaf(w4, f4.x, accx); accy = fmaf(w4, f4.y, accy);
            accx = fmaf(w5, f5.x, accx); accy = fmaf(w5, f5.y, accy);
            accx = fmaf(w6, f6.x, accx); accy = fmaf(w6, f6.y, accy);
            accx = fmaf(w7, f7.x, accx); accy = fmaf(w7, f7.y, accy);
        }
        for (; t < nn; ++t) {
            int src = __shfl(idx, t);
            float wt = __shfl(w, t);
            unsigned u = *(const unsigned*)(h + src * D + lane * 2);
            float2 f = bf2f(u);
            accx = fmaf(wt, f.x, accx);
            accy = fmaf(wt, f.y, accy);
        }
    }

    accx = fmaxf(accx + bias[lane * 2], 0.f);
    accy = fmaxf(accy + bias[lane * 2 + 1], 0.f);
    bf16x2 o = { (bf16)accx, (bf16)accy };
    *(bf16x2*)(out + v * D + lane * 2) = o;
}

__global__ __launch_bounds__(64) void pool_kernel(const bf16* __restrict__ h,
                                                  const int* __restrict__ starts,
                                                  float* __restrict__ pooled) {
    int g = blockIdx.x, lane = threadIdx.x;
    int s = starts[g], e = starts[g + 1];
    float ax = 0.f, ay = 0.f;
    for (int r = s; r < e; ++r) {
        unsigned u = *(const unsigned*)(h + r * D + lane * 2);
        float2 f = bf2f(u);
        ax += f.x; ay += f.y;
    }
    float c = fmaxf((float)(e - s), 1.0f);
    pooled[g * D + lane * 2]     = ax / c;
    pooled[g * D + lane * 2 + 1] = ay / c;
}

__global__ __launch_bounds__(256) void fc_kernel(const float* __restrict__ pooled,
                                                 const float* __restrict__ Wfc,
                                                 const float* __restrict__ bfc,
                                                 const float* __restrict__ Wfc2,
                                                 const float* __restrict__ bfc2,
                                                 float* __restrict__ out) {
    __shared__ float pr[D];
    __shared__ float hid[D_FF];
    int g = blockIdx.x, t = threadIdx.x;
    if (t < D) pr[t] = pooled[g * D + t];
    __syncthreads();
    float acc = bfc[t];
    for (int k = 0; k < D; ++k) acc = fmaf(pr[k], Wfc[k * D_FF + t], acc);
    hid[t] = fmaxf(acc, 0.f);
    __syncthreads();
    if (t < N_CLASSES) {
        float o = bfc2[t];
        for (int k = 0; k < D_FF; ++k) o = fmaf(hid[k], Wfc2[k * N_CLASSES + t], o);
        out[g * N_CLASSES + t] = o;
    }
}

// ---------------- launch ----------------

extern "C" void kernel_launch(void* const* d_in, const int* in_sizes, int n_in,
                              void* d_out, int out_size, void* d_ws, size_t ws_size,
                              hipStream_t stream) {
    const float* x     = (const float*)d_in[0];
    const int*   eidx  = (const int*)d_in[1];
    const int*   batch = (const int*)d_in[2];
    const float* W[3]  = { (const float*)d_in[3], (const float*)d_in[5], (const float*)d_in[7] };
    const float* b[3]  = { (const float*)d_in[4], (const float*)d_in[6], (const float*)d_in[8] };
    const float* Wfc   = (const float*)d_in[9];
    const float* bfc   = (const float*)d_in[10];
    const float* Wfc2  = (const float*)d_in[11];
    const float* bfc2  = (const float*)d_in[12];
    float* out = (float*)d_out;

    const int E = in_sizes[1] / 2;           // 3,200,000
    const int N = in_sizes[0] / D;           // 100,000
    const int* esrc = eidx;
    const int* edst = eidx + E;

    uint8_t* base = (uint8_t*)d_ws;
    size_t off = 0;
    auto alloc = [&](size_t bytes) -> void* {
        void* p = base + off;
        off = (off + bytes + 255) & ~(size_t)255;
        return p;
    };
    bf16*  hA      = (bf16*) alloc((size_t)N_PAD * D * 2);
    bf16*  hB      = (bf16*) alloc((size_t)N_PAD * D * 2);
    bf16*  Xb      = (bf16*) alloc((size_t)N_PAD * D * 2);
    bf16*  WT      = (bf16*) alloc((size_t)D * D * 2);
    int*   csrc    = (int*)  alloc((size_t)E * 4);
    int*   eoff    = (int*)  alloc((size_t)E * 4);
    int*   counts8 = (int*)  alloc((size_t)N * R * 4);
    int*   base8   = (int*)  alloc((size_t)N * R * 4);
    int*   counts  = (int*)  alloc((size_t)N * 4);
    int*   rowptr  = (int*)  alloc((size_t)(N + 1) * 4);
    float* dinv    = (float*)alloc((size_t)N * 4);
    int*   bsum    = (int*)  alloc(4096);
    int*   boff    = (int*)  alloc(4096);
    int*   starts  = (int*)  alloc((size_t)(N_GRAPHS + 1) * 4);
    float* pooled  = (float*)alloc((size_t)N_GRAPHS * D * 4);
    (void)ws_size; (void)n_in; (void)out_size;

    const int NB  = (N + 255) / 256;              // 391
    const int N8B = (N * R + 255) / 256;          // 3125
    const int EB  = (E + 255) / 256;              // 12500
    const int CB  = (N_PAD * D / 4 + 255) / 256;
    const int GB  = N_PAD / 64;                   // 1563
    const int SB  = (N + 3) / 4;                  // spmm blocks (4 nodes each)

    init_kernel<<<N8B, 256, 0, stream>>>(counts8, starts, N * R);
    hist_kernel<<<EB, 256, 0, stream>>>(edst, counts8, eoff, E);
    sum_kernel<<<NB, 256, 0, stream>>>(counts8, base8, counts, dinv, N);
    scan1<<<NB, 256, 0, stream>>>(counts, rowptr, bsum, N);
    scan2<<<1, 512, 0, stream>>>(bsum, boff, NB);
    scan3<<<NB, 256, 0, stream>>>(rowptr, boff, N);
    fill_edges<<<EB, 256, 0, stream>>>(esrc, edst, eoff, rowptr, base8, csrc, E);
    find_starts<<<NB, 256, 0, stream>>>(batch, starts, N);
    fix_starts<<<1, 64, 0, stream>>>(starts);

    cast4_kernel<<<CB, 256, 0, stream>>>(x, Xb, N * D, N_PAD * D);

    const bf16* layer_in = Xb;
    for (int l = 0; l < 3; ++l) {
        castWT_kernel<<<D, D, 0, stream>>>(W[l], WT);
        gemm_kernel<<<GB, 256, 0, stream>>>(layer_in, WT, hA);
        spmm_kernel<<<SB, 256, 0, stream>>>(hA, rowptr, csrc, dinv, b[l], hB, N);
        layer_in = hB;
    }

    pool_kernel<<<N_GRAPHS, 64, 0, stream>>>(hB, starts, pooled);
    fc_kernel<<<N_GRAPHS, 256, 0, stream>>>(pooled, Wfc, bfc, Wfc2, bfc2, out);
}

// Round 4
// 871.004 us; speedup vs baseline: 1.0283x; 1.0283x over previous
//
#include <hip/hip_runtime.h>
#include <hip/hip_bf16.h>

typedef __bf16 bf16;
typedef __attribute__((ext_vector_type(8))) __bf16 bf16x8;
typedef __attribute__((ext_vector_type(4))) __bf16 bf16x4;
typedef __attribute__((ext_vector_type(2))) __bf16 bf16x2;
typedef __attribute__((ext_vector_type(4))) float f32x4;

constexpr int N_NODES   = 100000;
constexpr int N_PAD     = 100032;   // multiple of 64 (GEMM block tile)
constexpr int D         = 128;
constexpr int D_FF      = 256;
constexpr int N_CLASSES = 26;
constexpr int N_GRAPHS  = 512;
constexpr int R         = 8;        // one histogram plane per XCD

// actual XCD id of the executing wave (HW-verified on gfx950, learn_hip m09)
__device__ inline int xcc_id() {
    int x;
    asm volatile("s_getreg_b32 %0, hwreg(HW_REG_XCC_ID, 0, 4)" : "=s"(x));
    return x & (R - 1);
}

__device__ inline float2 bf2f(unsigned u) {
    float lo = __uint_as_float(u << 16);
    float hi = __uint_as_float(u & 0xffff0000u);
    return make_float2(lo, hi);
}

// ---------------- graph preprocessing ----------------

__global__ void init_kernel(int* counts8, int* starts, int n8) {
    int i = blockIdx.x * 256 + threadIdx.x;
    if (i < n8) counts8[i] = 0;
    if (i <= N_GRAPHS) starts[i] = N_NODES;
}

// XCD-planar histogram: plane r = this wave's XCD -> counter lines are
// XCD-private, no cross-XCD line ping-pong. Plane id packed into eoff[26:24].
__global__ void hist_kernel(const int* __restrict__ edst, int* counts8,
                            int* __restrict__ eoff, int e, int n) {
    int i = blockIdx.x * 256 + threadIdx.x;
    int r = xcc_id();
    if (i < e) {
        int off = atomicAdd(&counts8[r * n + edst[i]], 1);
        eoff[i] = off | (r << 24);
    }
}

// per node: total count, exclusive prefix over planes, dinv
__global__ void sum_kernel(const int* __restrict__ counts8, int* __restrict__ base8,
                           int* __restrict__ counts, float* __restrict__ dinv, int n) {
    int i = blockIdx.x * 256 + threadIdx.x;
    if (i >= n) return;
    int run = 0;
#pragma unroll
    for (int r = 0; r < R; ++r) {
        base8[r * n + i] = run;
        run += counts8[r * n + i];
    }
    counts[i] = run;
    dinv[i] = 1.0f / sqrtf((float)(run + 1));  // +1 = self-loop
}

// 3-phase exclusive scan of counts -> rowptr
__global__ __launch_bounds__(256) void scan1(const int* __restrict__ counts,
                                             int* rowptr, int* bsum, int n) {
    __shared__ int sd[256];
    int i = blockIdx.x * 256 + threadIdx.x;
    int v = (i < n) ? counts[i] : 0;
    sd[threadIdx.x] = v; __syncthreads();
    for (int off = 1; off < 256; off <<= 1) {
        int t = (threadIdx.x >= off) ? sd[threadIdx.x - off] : 0;
        __syncthreads();
        sd[threadIdx.x] += t;
        __syncthreads();
    }
    if (i < n) rowptr[i + 1] = sd[threadIdx.x];
    if (threadIdx.x == 255) bsum[blockIdx.x] = sd[255];
}

__global__ __launch_bounds__(512) void scan2(const int* __restrict__ bsum,
                                             int* boff, int nb) {
    __shared__ int sd[512];
    int t = threadIdx.x;
    int v = (t < nb) ? bsum[t] : 0;
    sd[t] = v; __syncthreads();
    for (int off = 1; off < 512; off <<= 1) {
        int x = (t >= off) ? sd[t - off] : 0;
        __syncthreads();
        sd[t] += x;
        __syncthreads();
    }
    if (t < nb) boff[t] = sd[t] - v;  // exclusive
}

__global__ void scan3(int* rowptr, const int* __restrict__ boff, int n) {
    int i = blockIdx.x * 256 + threadIdx.x;
    if (i < n) rowptr[i + 1] += boff[blockIdx.x];
    if (i == 0) rowptr[0] = 0;
}

// single scattered 4B write per edge
__global__ void fill_edges(const int* __restrict__ esrc, const int* __restrict__ edst,
                           const int* __restrict__ eoff, const int* __restrict__ rowptr,
                           const int* __restrict__ base8, int* __restrict__ csrc,
                           int e, int n) {
    int i = blockIdx.x * 256 + threadIdx.x;
    if (i >= e) return;
    int pe = eoff[i];
    int r = pe >> 24;
    int off = pe & 0xFFFFFF;
    int d = edst[i];
    csrc[rowptr[d] + base8[r * n + d] + off] = esrc[i];
}

__global__ void find_starts(const int* __restrict__ batch, int* starts, int n) {
    int i = blockIdx.x * 256 + threadIdx.x;
    if (i >= n) return;
    int b = batch[i];
    if (i == 0 || batch[i - 1] != b) atomicMin(&starts[b], i);
}

__global__ void fix_starts(int* starts) {
    if (blockIdx.x == 0 && threadIdx.x == 0) {
        for (int g = N_GRAPHS - 1; g >= 0; --g)
            if (starts[g] > starts[g + 1]) starts[g] = starts[g + 1];
    }
}

// ---------------- dense compute ----------------

__global__ void cast4_kernel(const float* __restrict__ src, bf16* __restrict__ dst,
                             int nvalid, int ntotal) {
    int i = (blockIdx.x * 256 + threadIdx.x) * 4;
    if (i >= ntotal) return;
    float4 v = make_float4(0.f, 0.f, 0.f, 0.f);
    if (i < nvalid) v = *(const float4*)(src + i);
    bf16x4 o = { (bf16)v.x, (bf16)v.y, (bf16)v.z, (bf16)v.w };
    *(bf16x4*)(dst + i) = o;
}

__global__ void castWT_kernel(const float* __restrict__ W, bf16* __restrict__ WT) {
    int n = blockIdx.x, k = threadIdx.x;
    WT[n * D + k] = (bf16)W[k * D + n];
}

// C[Mpad x 128] = A[Mpad x 128] @ W[128 x 128], bf16 in/out, no LDS.
__global__ __launch_bounds__(256) void gemm_kernel(const bf16* __restrict__ A,
                                                   const bf16* __restrict__ WT,
                                                   bf16* __restrict__ C) {
    int wave = threadIdx.x >> 6;
    int lane = threadIdx.x & 63;
    int m16  = lane & 15;
    int quad = lane >> 4;
    int row0 = blockIdx.x * 64 + wave * 16;

    bf16x8 a[4];
    const bf16* arow = A + (row0 + m16) * D + quad * 8;
#pragma unroll
    for (int kt = 0; kt < 4; ++kt)
        a[kt] = *(const bf16x8*)(arow + kt * 32);

#pragma unroll
    for (int nt = 0; nt < 8; ++nt) {
        f32x4 acc = {0.f, 0.f, 0.f, 0.f};
        const bf16* brow = WT + (nt * 16 + m16) * D + quad * 8;
#pragma unroll
        for (int kt = 0; kt < 4; ++kt) {
            bf16x8 b = *(const bf16x8*)(brow + kt * 32);
            acc = __builtin_amdgcn_mfma_f32_16x16x32_bf16(a[kt], b, acc, 0, 0, 0);
        }
#pragma unroll
        for (int r = 0; r < 4; ++r)
            C[(row0 + quad * 4 + r) * D + nt * 16 + m16] = (bf16)acc[r];
    }
}

// out[v][:] = relu( dinv[v]^2*h[v] + sum_e dinv[src]*dinv[v]*h[src] + bias )
// 4 waves/block, one node per wave; lane covers dims {2*lane, 2*lane+1}
__global__ __launch_bounds__(256) void spmm_kernel(const bf16* __restrict__ h,
                                                   const int* __restrict__ rowptr,
                                                   const int* __restrict__ csrc,
                                                   const float* __restrict__ dinv,
                                                   const float* __restrict__ bias,
                                                   bf16* __restrict__ out, int n) {
    int v = blockIdx.x * 4 + (threadIdx.x >> 6);
    if (v >= n) return;
    int lane = threadIdx.x & 63;
    int s = rowptr[v], e = rowptr[v + 1];
    float dv = dinv[v];

    unsigned su = *(const unsigned*)(h + v * D + lane * 2);
    float2 sf = bf2f(su);
    float accx = dv * dv * sf.x;
    float accy = dv * dv * sf.y;

    for (int j0 = s; j0 < e; j0 += 64) {
        int nn = min(64, e - j0);
        int idx = 0; float w = 0.f;
        if (j0 + lane < e) { idx = csrc[j0 + lane]; w = dinv[idx] * dv; }
        int t = 0;
        for (; t + 8 <= nn; t += 8) {
            int s0 = __shfl(idx, t),     s1 = __shfl(idx, t + 1);
            int s2 = __shfl(idx, t + 2), s3 = __shfl(idx, t + 3);
            int s4 = __shfl(idx, t + 4), s5 = __shfl(idx, t + 5);
            int s6 = __shfl(idx, t + 6), s7 = __shfl(idx, t + 7);
            unsigned u0 = *(const unsigned*)(h + s0 * D + lane * 2);
            unsigned u1 = *(const unsigned*)(h + s1 * D + lane * 2);
            unsigned u2 = *(const unsigned*)(h + s2 * D + lane * 2);
            unsigned u3 = *(const unsigned*)(h + s3 * D + lane * 2);
            unsigned u4 = *(const unsigned*)(h + s4 * D + lane * 2);
            unsigned u5 = *(const unsigned*)(h + s5 * D + lane * 2);
            unsigned u6 = *(const unsigned*)(h + s6 * D + lane * 2);
            unsigned u7 = *(const unsigned*)(h + s7 * D + lane * 2);
            float w0 = __shfl(w, t),     w1 = __shfl(w, t + 1);
            float w2 = __shfl(w, t + 2), w3 = __shfl(w, t + 3);
            float w4 = __shfl(w, t + 4), w5 = __shfl(w, t + 5);
            float w6 = __shfl(w, t + 6), w7 = __shfl(w, t + 7);
            float2 f0 = bf2f(u0), f1 = bf2f(u1), f2 = bf2f(u2), f3 = bf2f(u3);
            float2 f4 = bf2f(u4), f5 = bf2f(u5), f6 = bf2f(u6), f7 = bf2f(u7);
            accx = fmaf(w0, f0.x, accx); accy = fmaf(w0, f0.y, accy);
            accx = fmaf(w1, f1.x, accx); accy = fmaf(w1, f1.y, accy);
            accx = fmaf(w2, f2.x, accx); accy = fmaf(w2, f2.y, accy);
            accx = fmaf(w3, f3.x, accx); accy = fmaf(w3, f3.y, accy);
            accx = fmaf(w4, f4.x, accx); accy = fmaf(w4, f4.y, accy);
            accx = fmaf(w5, f5.x, accx); accy = fmaf(w5, f5.y, accy);
            accx = fmaf(w6, f6.x, accx); accy = fmaf(w6, f6.y, accy);
            accx = fmaf(w7, f7.x, accx); accy = fmaf(w7, f7.y, accy);
        }
        for (; t < nn; ++t) {
            int src = __shfl(idx, t);
            float wt = __shfl(w, t);
            unsigned u = *(const unsigned*)(h + src * D + lane * 2);
            float2 f = bf2f(u);
            accx = fmaf(wt, f.x, accx);
            accy = fmaf(wt, f.y, accy);
        }
    }

    accx = fmaxf(accx + bias[lane * 2], 0.f);
    accy = fmaxf(accy + bias[lane * 2 + 1], 0.f);
    bf16x2 o = { (bf16)accx, (bf16)accy };
    *(bf16x2*)(out + v * D + lane * 2) = o;
}

__global__ __launch_bounds__(64) void pool_kernel(const bf16* __restrict__ h,
                                                  const int* __restrict__ starts,
                                                  float* __restrict__ pooled) {
    int g = blockIdx.x, lane = threadIdx.x;
    int s = starts[g], e = starts[g + 1];
    float ax = 0.f, ay = 0.f;
    for (int r = s; r < e; ++r) {
        unsigned u = *(const unsigned*)(h + r * D + lane * 2);
        float2 f = bf2f(u);
        ax += f.x; ay += f.y;
    }
    float c = fmaxf((float)(e - s), 1.0f);
    pooled[g * D + lane * 2]     = ax / c;
    pooled[g * D + lane * 2 + 1] = ay / c;
}

__global__ __launch_bounds__(256) void fc_kernel(const float* __restrict__ pooled,
                                                 const float* __restrict__ Wfc,
                                                 const float* __restrict__ bfc,
                                                 const float* __restrict__ Wfc2,
                                                 const float* __restrict__ bfc2,
                                                 float* __restrict__ out) {
    __shared__ float pr[D];
    __shared__ float hid[D_FF];
    int g = blockIdx.x, t = threadIdx.x;
    if (t < D) pr[t] = pooled[g * D + t];
    __syncthreads();
    float acc = bfc[t];
    for (int k = 0; k < D; ++k) acc = fmaf(pr[k], Wfc[k * D_FF + t], acc);
    hid[t] = fmaxf(acc, 0.f);
    __syncthreads();
    if (t < N_CLASSES) {
        float o = bfc2[t];
        for (int k = 0; k < D_FF; ++k) o = fmaf(hid[k], Wfc2[k * N_CLASSES + t], o);
        out[g * N_CLASSES + t] = o;
    }
}

// ---------------- launch ----------------

extern "C" void kernel_launch(void* const* d_in, const int* in_sizes, int n_in,
                              void* d_out, int out_size, void* d_ws, size_t ws_size,
                              hipStream_t stream) {
    const float* x     = (const float*)d_in[0];
    const int*   eidx  = (const int*)d_in[1];
    const int*   batch = (const int*)d_in[2];
    const float* W[3]  = { (const float*)d_in[3], (const float*)d_in[5], (const float*)d_in[7] };
    const float* b[3]  = { (const float*)d_in[4], (const float*)d_in[6], (const float*)d_in[8] };
    const float* Wfc   = (const float*)d_in[9];
    const float* bfc   = (const float*)d_in[10];
    const float* Wfc2  = (const float*)d_in[11];
    const float* bfc2  = (const float*)d_in[12];
    float* out = (float*)d_out;

    const int E = in_sizes[1] / 2;           // 3,200,000
    const int N = in_sizes[0] / D;           // 100,000
    const int* esrc = eidx;
    const int* edst = eidx + E;

    uint8_t* base = (uint8_t*)d_ws;
    size_t off = 0;
    auto alloc = [&](size_t bytes) -> void* {
        void* p = base + off;
        off = (off + bytes + 255) & ~(size_t)255;
        return p;
    };
    bf16*  hA      = (bf16*) alloc((size_t)N_PAD * D * 2);
    bf16*  hB      = (bf16*) alloc((size_t)N_PAD * D * 2);
    bf16*  Xb      = (bf16*) alloc((size_t)N_PAD * D * 2);
    bf16*  WT      = (bf16*) alloc((size_t)D * D * 2);
    int*   csrc    = (int*)  alloc((size_t)E * 4);
    int*   eoff    = (int*)  alloc((size_t)E * 4);
    int*   counts8 = (int*)  alloc((size_t)N * R * 4);
    int*   base8   = (int*)  alloc((size_t)N * R * 4);
    int*   counts  = (int*)  alloc((size_t)N * 4);
    int*   rowptr  = (int*)  alloc((size_t)(N + 1) * 4);
    float* dinv    = (float*)alloc((size_t)N * 4);
    int*   bsum    = (int*)  alloc(4096);
    int*   boff    = (int*)  alloc(4096);
    int*   starts  = (int*)  alloc((size_t)(N_GRAPHS + 1) * 4);
    float* pooled  = (float*)alloc((size_t)N_GRAPHS * D * 4);
    (void)ws_size; (void)n_in; (void)out_size;

    const int NB  = (N + 255) / 256;              // 391
    const int N8B = (N * R + 255) / 256;          // 3125
    const int EB  = (E + 255) / 256;              // 12500
    const int CB  = (N_PAD * D / 4 + 255) / 256;
    const int GB  = N_PAD / 64;                   // 1563
    const int SB  = (N + 3) / 4;                  // spmm blocks (4 nodes each)

    init_kernel<<<N8B, 256, 0, stream>>>(counts8, starts, N * R);
    hist_kernel<<<EB, 256, 0, stream>>>(edst, counts8, eoff, E, N);
    sum_kernel<<<NB, 256, 0, stream>>>(counts8, base8, counts, dinv, N);
    scan1<<<NB, 256, 0, stream>>>(counts, rowptr, bsum, N);
    scan2<<<1, 512, 0, stream>>>(bsum, boff, NB);
    scan3<<<NB, 256, 0, stream>>>(rowptr, boff, N);
    fill_edges<<<EB, 256, 0, stream>>>(esrc, edst, eoff, rowptr, base8, csrc, E, N);
    find_starts<<<NB, 256, 0, stream>>>(batch, starts, N);
    fix_starts<<<1, 64, 0, stream>>>(starts);

    cast4_kernel<<<CB, 256, 0, stream>>>(x, Xb, N * D, N_PAD * D);

    const bf16* layer_in = Xb;
    for (int l = 0; l < 3; ++l) {
        castWT_kernel<<<D, D, 0, stream>>>(W[l], WT);
        gemm_kernel<<<GB, 256, 0, stream>>>(layer_in, WT, hA);
        spmm_kernel<<<SB, 256, 0, stream>>>(hA, rowptr, csrc, dinv, b[l], hB, N);
        layer_in = hB;
    }

    pool_kernel<<<N_GRAPHS, 64, 0, stream>>>(hB, starts, pooled);
    fc_kernel<<<N_GRAPHS, 256, 0, stream>>>(pooled, Wfc, bfc, Wfc2, bfc2, out);
}

// Round 5
// 792.997 us; speedup vs baseline: 1.1294x; 1.0984x over previous
//
#include <hip/hip_runtime.h>
#include <hip/hip_bf16.h>

typedef __bf16 bf16;
typedef __attribute__((ext_vector_type(8))) __bf16 bf16x8;
typedef __attribute__((ext_vector_type(4))) __bf16 bf16x4;
typedef __attribute__((ext_vector_type(2))) __bf16 bf16x2;
typedef __attribute__((ext_vector_type(4))) float f32x4;

constexpr int N_NODES   = 100000;
constexpr int N_PAD     = 100032;   // multiple of 64 (GEMM block tile)
constexpr int D         = 128;
constexpr int D_FF      = 256;
constexpr int N_CLASSES = 26;
constexpr int N_GRAPHS  = 512;
constexpr int NB1       = 1024;                      // partition blocks
constexpr int NBUCK     = (N_NODES + 511) / 512;     // 196 dst-buckets of 512 nodes

__device__ inline float2 bf2f(unsigned u) {
    float lo = __uint_as_float(u << 16);
    float hi = __uint_as_float(u & 0xffff0000u);
    return make_float2(lo, hi);
}

// ---------------- CSR build: atomic-free bucket counting sort ----------------

// P1: per-block LDS histogram over dst buckets (bucket = dst >> 9)
__global__ __launch_bounds__(256) void p1_hist(const int* __restrict__ edst,
                                               int* __restrict__ gcount, int e) {
    __shared__ int cnt[NBUCK];
    for (int t = threadIdx.x; t < NBUCK; t += 256) cnt[t] = 0;
    __syncthreads();
    int chunk = (e + NB1 - 1) / NB1;
    int lo = blockIdx.x * chunk;
    int hi = min(e, lo + chunk);
    for (int i = lo + threadIdx.x; i < hi; i += 256)
        atomicAdd(&cnt[edst[i] >> 9], 1);
    __syncthreads();
    for (int t = threadIdx.x; t < NBUCK; t += 256)
        gcount[t * NB1 + blockIdx.x] = cnt[t];
}

// 3-phase exclusive scan: out[0]=0, out[i+1]=incl[i] (+ block offsets)
__global__ __launch_bounds__(256) void scan1(const int* __restrict__ in,
                                             int* out, int* bsum, int n) {
    __shared__ int sd[256];
    int i = blockIdx.x * 256 + threadIdx.x;
    int v = (i < n) ? in[i] : 0;
    sd[threadIdx.x] = v; __syncthreads();
    for (int off = 1; off < 256; off <<= 1) {
        int t = (threadIdx.x >= off) ? sd[threadIdx.x - off] : 0;
        __syncthreads();
        sd[threadIdx.x] += t;
        __syncthreads();
    }
    if (i < n) out[i + 1] = sd[threadIdx.x];
    if (threadIdx.x == 255) bsum[blockIdx.x] = sd[255];
}

__global__ __launch_bounds__(1024) void scan2(const int* __restrict__ bsum,
                                              int* boff, int nb) {
    __shared__ int sd[1024];
    int t = threadIdx.x;
    int v = (t < nb) ? bsum[t] : 0;
    sd[t] = v; __syncthreads();
    for (int off = 1; off < 1024; off <<= 1) {
        int x = (t >= off) ? sd[t - off] : 0;
        __syncthreads();
        sd[t] += x;
        __syncthreads();
    }
    if (t < nb) boff[t] = sd[t] - v;  // exclusive
}

__global__ void scan3(int* out, const int* __restrict__ boff, int n) {
    int i = blockIdx.x * 256 + threadIdx.x;
    if (i < n) out[i + 1] += boff[blockIdx.x];
    if (i == 0) out[0] = 0;
}

// P3: scatter edges into bucket-contiguous ebuf; pack (src<<9)|(dst&511)
__global__ __launch_bounds__(256) void p3_scatter(const int* __restrict__ esrc,
                                                  const int* __restrict__ edst,
                                                  const int* __restrict__ gbase,
                                                  int* __restrict__ ebuf, int e) {
    __shared__ int cur[NBUCK];
    for (int t = threadIdx.x; t < NBUCK; t += 256)
        cur[t] = gbase[t * NB1 + blockIdx.x];
    __syncthreads();
    int chunk = (e + NB1 - 1) / NB1;
    int lo = blockIdx.x * chunk;
    int hi = min(e, lo + chunk);
    for (int i = lo + threadIdx.x; i < hi; i += 256) {
        int d = edst[i], s = esrc[i];
        int pos = atomicAdd(&cur[d >> 9], 1);   // LDS atomic
        ebuf[pos] = (s << 9) | (d & 511);
    }
}

// P4: per-bucket node degree + bucket-local exclusive rowptr (LDS) + dinv
__global__ __launch_bounds__(256) void p4_count(const int* __restrict__ ebuf,
                                                const int* __restrict__ gbase,
                                                int* __restrict__ localr,
                                                float* __restrict__ dinv,
                                                int* __restrict__ btotal, int e, int n) {
    __shared__ int cnt[512];
    __shared__ int ps[256];
    int b = blockIdx.x, t = threadIdx.x;
    cnt[t] = 0; cnt[t + 256] = 0;
    __syncthreads();
    int lo = gbase[b * NB1];
    int hi = (b + 1 < NBUCK) ? gbase[(b + 1) * NB1] : e;
    for (int i = lo + t; i < hi; i += 256)
        atomicAdd(&cnt[ebuf[i] & 511], 1);      // LDS atomic
    __syncthreads();
    int a0 = cnt[t * 2], a1 = cnt[t * 2 + 1];
    ps[t] = a0 + a1;
    __syncthreads();
    for (int off = 1; off < 256; off <<= 1) {
        int v = (t >= off) ? ps[t - off] : 0;
        __syncthreads();
        ps[t] += v;
        __syncthreads();
    }
    int pexcl = (t > 0) ? ps[t - 1] : 0;
    int node0 = b * 512 + t * 2;
    if (node0 < n) {
        localr[node0] = pexcl;
        dinv[node0] = 1.0f / sqrtf((float)(a0 + 1));   // +1 self-loop
    }
    if (node0 + 1 < n) {
        localr[node0 + 1] = pexcl + a0;
        dinv[node0 + 1] = 1.0f / sqrtf((float)(a1 + 1));
    }
    if (t == 255) btotal[b] = ps[255];
}

// P4b: scan of 196 bucket totals
__global__ __launch_bounds__(256) void p4b_scan(const int* __restrict__ btotal,
                                                int* __restrict__ bbase,
                                                int* __restrict__ rowptr, int e, int n) {
    __shared__ int sd[256];
    int t = threadIdx.x;
    int v = (t < NBUCK) ? btotal[t] : 0;
    sd[t] = v; __syncthreads();
    for (int off = 1; off < 256; off <<= 1) {
        int x = (t >= off) ? sd[t - off] : 0;
        __syncthreads();
        sd[t] += x;
        __syncthreads();
    }
    if (t < NBUCK) bbase[t] = sd[t] - v;
    if (t == 0) rowptr[n] = e;
}

// P5: per-bucket CSR fill (LDS cursors; csrc writes stay in a 64KB L2 window)
__global__ __launch_bounds__(256) void p5_fill(const int* __restrict__ ebuf,
                                               const int* __restrict__ gbase,
                                               const int* __restrict__ localr,
                                               const int* __restrict__ bbase,
                                               int* __restrict__ rowptr,
                                               int* __restrict__ csrc, int e, int n) {
    __shared__ int cur[512];
    int b = blockIdx.x, t = threadIdx.x;
    int bb = bbase[b];
    for (int j = t; j < 512; j += 256) {
        int node = b * 512 + j;
        int v = 0;
        if (node < n) {
            v = bb + localr[node];
            rowptr[node] = v;
        }
        cur[j] = v;
    }
    __syncthreads();
    int lo = gbase[b * NB1];
    int hi = (b + 1 < NBUCK) ? gbase[(b + 1) * NB1] : e;
    for (int i = lo + t; i < hi; i += 256) {
        int pe = ebuf[i];
        int pos = atomicAdd(&cur[pe & 511], 1);  // LDS atomic
        csrc[pos] = pe >> 9;
    }
}

// ---------------- pooling index ----------------

__global__ void init_starts(int* starts) {
    int i = blockIdx.x * 256 + threadIdx.x;
    if (i <= N_GRAPHS) starts[i] = N_NODES;
}

__global__ void find_starts(const int* __restrict__ batch, int* starts, int n) {
    int i = blockIdx.x * 256 + threadIdx.x;
    if (i >= n) return;
    int b = batch[i];
    if (i == 0 || batch[i - 1] != b) atomicMin(&starts[b], i);
}

__global__ void fix_starts(int* starts) {
    if (blockIdx.x == 0 && threadIdx.x == 0) {
        for (int g = N_GRAPHS - 1; g >= 0; --g)
            if (starts[g] > starts[g + 1]) starts[g] = starts[g + 1];
    }
}

// ---------------- dense compute ----------------

__global__ void cast4_kernel(const float* __restrict__ src, bf16* __restrict__ dst,
                             int nvalid, int ntotal) {
    int i = (blockIdx.x * 256 + threadIdx.x) * 4;
    if (i >= ntotal) return;
    float4 v = make_float4(0.f, 0.f, 0.f, 0.f);
    if (i < nvalid) v = *(const float4*)(src + i);
    bf16x4 o = { (bf16)v.x, (bf16)v.y, (bf16)v.z, (bf16)v.w };
    *(bf16x4*)(dst + i) = o;
}

__global__ void castWT_kernel(const float* __restrict__ W, bf16* __restrict__ WT) {
    int n = blockIdx.x, k = threadIdx.x;
    WT[n * D + k] = (bf16)W[k * D + n];
}

// C[Mpad x 128] = A[Mpad x 128] @ W[128 x 128], bf16 in/out, no LDS.
__global__ __launch_bounds__(256) void gemm_kernel(const bf16* __restrict__ A,
                                                   const bf16* __restrict__ WT,
                                                   bf16* __restrict__ C) {
    int wave = threadIdx.x >> 6;
    int lane = threadIdx.x & 63;
    int m16  = lane & 15;
    int quad = lane >> 4;
    int row0 = blockIdx.x * 64 + wave * 16;

    bf16x8 a[4];
    const bf16* arow = A + (row0 + m16) * D + quad * 8;
#pragma unroll
    for (int kt = 0; kt < 4; ++kt)
        a[kt] = *(const bf16x8*)(arow + kt * 32);

#pragma unroll
    for (int nt = 0; nt < 8; ++nt) {
        f32x4 acc = {0.f, 0.f, 0.f, 0.f};
        const bf16* brow = WT + (nt * 16 + m16) * D + quad * 8;
#pragma unroll
        for (int kt = 0; kt < 4; ++kt) {
            bf16x8 b = *(const bf16x8*)(brow + kt * 32);
            acc = __builtin_amdgcn_mfma_f32_16x16x32_bf16(a[kt], b, acc, 0, 0, 0);
        }
#pragma unroll
        for (int r = 0; r < 4; ++r)
            C[(row0 + quad * 4 + r) * D + nt * 16 + m16] = (bf16)acc[r];
    }
}

// out[v][:] = relu( dinv[v]^2*h[v] + sum_e dinv[src]*dinv[v]*h[src] + bias )
// 4 waves/block, one node per wave; lane covers dims {2*lane, 2*lane+1}
__global__ __launch_bounds__(256) void spmm_kernel(const bf16* __restrict__ h,
                                                   const int* __restrict__ rowptr,
                                                   const int* __restrict__ csrc,
                                                   const float* __restrict__ dinv,
                                                   const float* __restrict__ bias,
                                                   bf16* __restrict__ out, int n) {
    int v = blockIdx.x * 4 + (threadIdx.x >> 6);
    if (v >= n) return;
    int lane = threadIdx.x & 63;
    int s = rowptr[v], e = rowptr[v + 1];
    float dv = dinv[v];

    unsigned su = *(const unsigned*)(h + v * D + lane * 2);
    float2 sf = bf2f(su);
    float accx = dv * dv * sf.x;
    float accy = dv * dv * sf.y;

    for (int j0 = s; j0 < e; j0 += 64) {
        int nn = min(64, e - j0);
        int idx = 0; float w = 0.f;
        if (j0 + lane < e) { idx = csrc[j0 + lane]; w = dinv[idx] * dv; }
        int t = 0;
        for (; t + 8 <= nn; t += 8) {
            int s0 = __shfl(idx, t),     s1 = __shfl(idx, t + 1);
            int s2 = __shfl(idx, t + 2), s3 = __shfl(idx, t + 3);
            int s4 = __shfl(idx, t + 4), s5 = __shfl(idx, t + 5);
            int s6 = __shfl(idx, t + 6), s7 = __shfl(idx, t + 7);
            unsigned u0 = *(const unsigned*)(h + s0 * D + lane * 2);
            unsigned u1 = *(const unsigned*)(h + s1 * D + lane * 2);
            unsigned u2 = *(const unsigned*)(h + s2 * D + lane * 2);
            unsigned u3 = *(const unsigned*)(h + s3 * D + lane * 2);
            unsigned u4 = *(const unsigned*)(h + s4 * D + lane * 2);
            unsigned u5 = *(const unsigned*)(h + s5 * D + lane * 2);
            unsigned u6 = *(const unsigned*)(h + s6 * D + lane * 2);
            unsigned u7 = *(const unsigned*)(h + s7 * D + lane * 2);
            float w0 = __shfl(w, t),     w1 = __shfl(w, t + 1);
            float w2 = __shfl(w, t + 2), w3 = __shfl(w, t + 3);
            float w4 = __shfl(w, t + 4), w5 = __shfl(w, t + 5);
            float w6 = __shfl(w, t + 6), w7 = __shfl(w, t + 7);
            float2 f0 = bf2f(u0), f1 = bf2f(u1), f2 = bf2f(u2), f3 = bf2f(u3);
            float2 f4 = bf2f(u4), f5 = bf2f(u5), f6 = bf2f(u6), f7 = bf2f(u7);
            accx = fmaf(w0, f0.x, accx); accy = fmaf(w0, f0.y, accy);
            accx = fmaf(w1, f1.x, accx); accy = fmaf(w1, f1.y, accy);
            accx = fmaf(w2, f2.x, accx); accy = fmaf(w2, f2.y, accy);
            accx = fmaf(w3, f3.x, accx); accy = fmaf(w3, f3.y, accy);
            accx = fmaf(w4, f4.x, accx); accy = fmaf(w4, f4.y, accy);
            accx = fmaf(w5, f5.x, accx); accy = fmaf(w5, f5.y, accy);
            accx = fmaf(w6, f6.x, accx); accy = fmaf(w6, f6.y, accy);
            accx = fmaf(w7, f7.x, accx); accy = fmaf(w7, f7.y, accy);
        }
        for (; t < nn; ++t) {
            int src = __shfl(idx, t);
            float wt = __shfl(w, t);
            unsigned u = *(const unsigned*)(h + src * D + lane * 2);
            float2 f = bf2f(u);
            accx = fmaf(wt, f.x, accx);
            accy = fmaf(wt, f.y, accy);
        }
    }

    accx = fmaxf(accx + bias[lane * 2], 0.f);
    accy = fmaxf(accy + bias[lane * 2 + 1], 0.f);
    bf16x2 o = { (bf16)accx, (bf16)accy };
    *(bf16x2*)(out + v * D + lane * 2) = o;
}

__global__ __launch_bounds__(64) void pool_kernel(const bf16* __restrict__ h,
                                                  const int* __restrict__ starts,
                                                  float* __restrict__ pooled) {
    int g = blockIdx.x, lane = threadIdx.x;
    int s = starts[g], e = starts[g + 1];
    float ax = 0.f, ay = 0.f;
    for (int r = s; r < e; ++r) {
        unsigned u = *(const unsigned*)(h + r * D + lane * 2);
        float2 f = bf2f(u);
        ax += f.x; ay += f.y;
    }
    float c = fmaxf((float)(e - s), 1.0f);
    pooled[g * D + lane * 2]     = ax / c;
    pooled[g * D + lane * 2 + 1] = ay / c;
}

__global__ __launch_bounds__(256) void fc_kernel(const float* __restrict__ pooled,
                                                 const float* __restrict__ Wfc,
                                                 const float* __restrict__ bfc,
                                                 const float* __restrict__ Wfc2,
                                                 const float* __restrict__ bfc2,
                                                 float* __restrict__ out) {
    __shared__ float pr[D];
    __shared__ float hid[D_FF];
    int g = blockIdx.x, t = threadIdx.x;
    if (t < D) pr[t] = pooled[g * D + t];
    __syncthreads();
    float acc = bfc[t];
    for (int k = 0; k < D; ++k) acc = fmaf(pr[k], Wfc[k * D_FF + t], acc);
    hid[t] = fmaxf(acc, 0.f);
    __syncthreads();
    if (t < N_CLASSES) {
        float o = bfc2[t];
        for (int k = 0; k < D_FF; ++k) o = fmaf(hid[k], Wfc2[k * N_CLASSES + t], o);
        out[g * N_CLASSES + t] = o;
    }
}

// ---------------- launch ----------------

extern "C" void kernel_launch(void* const* d_in, const int* in_sizes, int n_in,
                              void* d_out, int out_size, void* d_ws, size_t ws_size,
                              hipStream_t stream) {
    const float* x     = (const float*)d_in[0];
    const int*   eidx  = (const int*)d_in[1];
    const int*   batch = (const int*)d_in[2];
    const float* W[3]  = { (const float*)d_in[3], (const float*)d_in[5], (const float*)d_in[7] };
    const float* b[3]  = { (const float*)d_in[4], (const float*)d_in[6], (const float*)d_in[8] };
    const float* Wfc   = (const float*)d_in[9];
    const float* bfc   = (const float*)d_in[10];
    const float* Wfc2  = (const float*)d_in[11];
    const float* bfc2  = (const float*)d_in[12];
    float* out = (float*)d_out;

    const int E = in_sizes[1] / 2;           // 3,200,000
    const int N = in_sizes[0] / D;           // 100,000
    const int* esrc = eidx;
    const int* edst = eidx + E;

    uint8_t* base = (uint8_t*)d_ws;
    size_t off = 0;
    auto alloc = [&](size_t bytes) -> void* {
        void* p = base + off;
        off = (off + bytes + 255) & ~(size_t)255;
        return p;
    };
    bf16*  hA     = (bf16*) alloc((size_t)N_PAD * D * 2);
    bf16*  hB     = (bf16*) alloc((size_t)N_PAD * D * 2);
    bf16*  Xb     = (bf16*) alloc((size_t)N_PAD * D * 2);
    bf16*  WT     = (bf16*) alloc((size_t)D * D * 2);
    int*   csrc   = (int*)  alloc((size_t)E * 4);
    int*   ebuf   = (int*)  alloc((size_t)E * 4);
    int*   gcount = (int*)  alloc((size_t)NBUCK * NB1 * 4);
    int*   gbase  = (int*)  alloc((size_t)(NBUCK * NB1 + 1) * 4);
    int*   localr = (int*)  alloc((size_t)N * 4);
    int*   rowptr = (int*)  alloc((size_t)(N + 1) * 4);
    float* dinv   = (float*)alloc((size_t)N * 4);
    int*   btotal = (int*)  alloc(1024);
    int*   bbase  = (int*)  alloc(1024);
    int*   bsum   = (int*)  alloc(4096);
    int*   boff   = (int*)  alloc(4096);
    int*   starts = (int*)  alloc((size_t)(N_GRAPHS + 1) * 4);
    float* pooled = (float*)alloc((size_t)N_GRAPHS * D * 4);
    (void)ws_size; (void)n_in; (void)out_size;

    const int NB  = (N + 255) / 256;                    // 391
    const int EB  = (E + 255) / 256;
    const int CB  = (N_PAD * D / 4 + 255) / 256;
    const int GB  = N_PAD / 64;                         // 1563
    const int SB  = (N + 3) / 4;                        // spmm blocks
    const int GCN = NBUCK * NB1;                        // 200704
    const int GCB = (GCN + 255) / 256;                  // 784
    (void)EB;

    // CSR build (atomic-free, LDS counting sort)
    p1_hist<<<NB1, 256, 0, stream>>>(edst, gcount, E);
    scan1<<<GCB, 256, 0, stream>>>(gcount, gbase, bsum, GCN);
    scan2<<<1, 1024, 0, stream>>>(bsum, boff, GCB);
    scan3<<<GCB, 256, 0, stream>>>(gbase, boff, GCN);
    p3_scatter<<<NB1, 256, 0, stream>>>(esrc, edst, gbase, ebuf, E);
    p4_count<<<NBUCK, 256, 0, stream>>>(ebuf, gbase, localr, dinv, btotal, E, N);
    p4b_scan<<<1, 256, 0, stream>>>(btotal, bbase, rowptr, E, N);
    p5_fill<<<NBUCK, 256, 0, stream>>>(ebuf, gbase, localr, bbase, rowptr, csrc, E, N);

    // pooling segments
    init_starts<<<3, 256, 0, stream>>>(starts);
    find_starts<<<NB, 256, 0, stream>>>(batch, starts, N);
    fix_starts<<<1, 64, 0, stream>>>(starts);

    cast4_kernel<<<CB, 256, 0, stream>>>(x, Xb, N * D, N_PAD * D);

    const bf16* layer_in = Xb;
    for (int l = 0; l < 3; ++l) {
        castWT_kernel<<<D, D, 0, stream>>>(W[l], WT);
        gemm_kernel<<<GB, 256, 0, stream>>>(layer_in, WT, hA);
        spmm_kernel<<<SB, 256, 0, stream>>>(hA, rowptr, csrc, dinv, b[l], hB, N);
        layer_in = hB;
    }

    pool_kernel<<<N_GRAPHS, 64, 0, stream>>>(hB, starts, pooled);
    fc_kernel<<<N_GRAPHS, 256, 0, stream>>>(pooled, Wfc, bfc, Wfc2, bfc2, out);
}

// Round 6
// 781.711 us; speedup vs baseline: 1.1458x; 1.0144x over previous
//
#include <hip/hip_runtime.h>
#include <hip/hip_bf16.h>

typedef __bf16 bf16;
typedef __attribute__((ext_vector_type(8))) __bf16 bf16x8;
typedef __attribute__((ext_vector_type(4))) __bf16 bf16x4;
typedef __attribute__((ext_vector_type(2))) __bf16 bf16x2;
typedef __attribute__((ext_vector_type(4))) float f32x4;

constexpr int N_NODES   = 100000;
constexpr int N_PAD     = 100032;   // multiple of 64 (GEMM block tile)
constexpr int D         = 128;
constexpr int D_FF      = 256;
constexpr int N_CLASSES = 26;
constexpr int N_GRAPHS  = 512;
constexpr int NB1       = 1024;                      // partition blocks
constexpr int NBUCK     = (N_NODES + 511) / 512;     // 196 dst-buckets of 512 nodes

__device__ inline float2 bf2f(unsigned u) {
    float lo = __uint_as_float(u << 16);
    float hi = __uint_as_float(u & 0xffff0000u);
    return make_float2(lo, hi);
}

// ---------------- CSR build: atomic-free bucket counting sort ----------------

// P1: per-block LDS histogram over dst buckets (bucket = dst >> 9)
__global__ __launch_bounds__(256) void p1_hist(const int* __restrict__ edst,
                                               int* __restrict__ gcount, int e) {
    __shared__ int cnt[NBUCK];
    for (int t = threadIdx.x; t < NBUCK; t += 256) cnt[t] = 0;
    __syncthreads();
    int chunk = (e + NB1 - 1) / NB1;
    int lo = blockIdx.x * chunk;
    int hi = min(e, lo + chunk);
    for (int i = lo + threadIdx.x; i < hi; i += 256)
        atomicAdd(&cnt[edst[i] >> 9], 1);
    __syncthreads();
    for (int t = threadIdx.x; t < NBUCK; t += 256)
        gcount[t * NB1 + blockIdx.x] = cnt[t];
}

// 3-phase exclusive scan: out[0]=0, out[i+1]=incl[i] (+ block offsets)
__global__ __launch_bounds__(256) void scan1(const int* __restrict__ in,
                                             int* out, int* bsum, int n) {
    __shared__ int sd[256];
    int i = blockIdx.x * 256 + threadIdx.x;
    int v = (i < n) ? in[i] : 0;
    sd[threadIdx.x] = v; __syncthreads();
    for (int off = 1; off < 256; off <<= 1) {
        int t = (threadIdx.x >= off) ? sd[threadIdx.x - off] : 0;
        __syncthreads();
        sd[threadIdx.x] += t;
        __syncthreads();
    }
    if (i < n) out[i + 1] = sd[threadIdx.x];
    if (threadIdx.x == 255) bsum[blockIdx.x] = sd[255];
}

__global__ __launch_bounds__(1024) void scan2(const int* __restrict__ bsum,
                                              int* boff, int nb) {
    __shared__ int sd[1024];
    int t = threadIdx.x;
    int v = (t < nb) ? bsum[t] : 0;
    sd[t] = v; __syncthreads();
    for (int off = 1; off < 1024; off <<= 1) {
        int x = (t >= off) ? sd[t - off] : 0;
        __syncthreads();
        sd[t] += x;
        __syncthreads();
    }
    if (t < nb) boff[t] = sd[t] - v;  // exclusive
}

__global__ void scan3(int* out, const int* __restrict__ boff, int n) {
    int i = blockIdx.x * 256 + threadIdx.x;
    if (i < n) out[i + 1] += boff[blockIdx.x];
    if (i == 0) out[0] = 0;
}

// P3: scatter edges into bucket-contiguous ebuf; pack (src<<9)|(dst&511)
__global__ __launch_bounds__(256) void p3_scatter(const int* __restrict__ esrc,
                                                  const int* __restrict__ edst,
                                                  const int* __restrict__ gbase,
                                                  int* __restrict__ ebuf, int e) {
    __shared__ int cur[NBUCK];
    for (int t = threadIdx.x; t < NBUCK; t += 256)
        cur[t] = gbase[t * NB1 + blockIdx.x];
    __syncthreads();
    int chunk = (e + NB1 - 1) / NB1;
    int lo = blockIdx.x * chunk;
    int hi = min(e, lo + chunk);
    for (int i = lo + threadIdx.x; i < hi; i += 256) {
        int d = edst[i], s = esrc[i];
        int pos = atomicAdd(&cur[d >> 9], 1);   // LDS atomic
        ebuf[pos] = (s << 9) | (d & 511);
    }
}

// P4: per-bucket node degree + bucket-local exclusive rowptr (LDS) + dinv
__global__ __launch_bounds__(256) void p4_count(const int* __restrict__ ebuf,
                                                const int* __restrict__ gbase,
                                                int* __restrict__ localr,
                                                float* __restrict__ dinv,
                                                int* __restrict__ btotal, int e, int n) {
    __shared__ int cnt[512];
    __shared__ int ps[256];
    int b = blockIdx.x, t = threadIdx.x;
    cnt[t] = 0; cnt[t + 256] = 0;
    __syncthreads();
    int lo = gbase[b * NB1];
    int hi = (b + 1 < NBUCK) ? gbase[(b + 1) * NB1] : e;
    for (int i = lo + t; i < hi; i += 256)
        atomicAdd(&cnt[ebuf[i] & 511], 1);      // LDS atomic
    __syncthreads();
    int a0 = cnt[t * 2], a1 = cnt[t * 2 + 1];
    ps[t] = a0 + a1;
    __syncthreads();
    for (int off = 1; off < 256; off <<= 1) {
        int v = (t >= off) ? ps[t - off] : 0;
        __syncthreads();
        ps[t] += v;
        __syncthreads();
    }
    int pexcl = (t > 0) ? ps[t - 1] : 0;
    int node0 = b * 512 + t * 2;
    if (node0 < n) {
        localr[node0] = pexcl;
        dinv[node0] = 1.0f / sqrtf((float)(a0 + 1));   // +1 self-loop
    }
    if (node0 + 1 < n) {
        localr[node0 + 1] = pexcl + a0;
        dinv[node0 + 1] = 1.0f / sqrtf((float)(a1 + 1));
    }
    if (t == 255) btotal[b] = ps[255];
}

// P4b: scan of 196 bucket totals
__global__ __launch_bounds__(256) void p4b_scan(const int* __restrict__ btotal,
                                                int* __restrict__ bbase,
                                                int* __restrict__ rowptr, int e, int n) {
    __shared__ int sd[256];
    int t = threadIdx.x;
    int v = (t < NBUCK) ? btotal[t] : 0;
    sd[t] = v; __syncthreads();
    for (int off = 1; off < 256; off <<= 1) {
        int x = (t >= off) ? sd[t - off] : 0;
        __syncthreads();
        sd[t] += x;
        __syncthreads();
    }
    if (t < NBUCK) bbase[t] = sd[t] - v;
    if (t == 0) rowptr[n] = e;
}

// P5: per-bucket CSR fill (LDS cursors; csrc writes stay in a 64KB L2 window)
__global__ __launch_bounds__(256) void p5_fill(const int* __restrict__ ebuf,
                                               const int* __restrict__ gbase,
                                               const int* __restrict__ localr,
                                               const int* __restrict__ bbase,
                                               int* __restrict__ rowptr,
                                               int* __restrict__ csrc, int e, int n) {
    __shared__ int cur[512];
    int b = blockIdx.x, t = threadIdx.x;
    int bb = bbase[b];
    for (int j = t; j < 512; j += 256) {
        int node = b * 512 + j;
        int v = 0;
        if (node < n) {
            v = bb + localr[node];
            rowptr[node] = v;
        }
        cur[j] = v;
    }
    __syncthreads();
    int lo = gbase[b * NB1];
    int hi = (b + 1 < NBUCK) ? gbase[(b + 1) * NB1] : e;
    for (int i = lo + t; i < hi; i += 256) {
        int pe = ebuf[i];
        int pos = atomicAdd(&cur[pe & 511], 1);  // LDS atomic
        csrc[pos] = pe >> 9;
    }
}

// ---------------- pooling index ----------------

__global__ void init_starts(int* starts) {
    int i = blockIdx.x * 256 + threadIdx.x;
    if (i <= N_GRAPHS) starts[i] = N_NODES;
}

__global__ void find_starts(const int* __restrict__ batch, int* starts, int n) {
    int i = blockIdx.x * 256 + threadIdx.x;
    if (i >= n) return;
    int b = batch[i];
    if (i == 0 || batch[i - 1] != b) atomicMin(&starts[b], i);
}

__global__ void fix_starts(int* starts) {
    if (blockIdx.x == 0 && threadIdx.x == 0) {
        for (int g = N_GRAPHS - 1; g >= 0; --g)
            if (starts[g] > starts[g + 1]) starts[g] = starts[g + 1];
    }
}

// ---------------- dense compute ----------------

__global__ void cast4_kernel(const float* __restrict__ src, bf16* __restrict__ dst,
                             int nvalid, int ntotal) {
    int i = (blockIdx.x * 256 + threadIdx.x) * 4;
    if (i >= ntotal) return;
    float4 v = make_float4(0.f, 0.f, 0.f, 0.f);
    if (i < nvalid) v = *(const float4*)(src + i);
    bf16x4 o = { (bf16)v.x, (bf16)v.y, (bf16)v.z, (bf16)v.w };
    *(bf16x4*)(dst + i) = o;
}

__global__ void castWT_kernel(const float* __restrict__ W, bf16* __restrict__ WT) {
    int n = blockIdx.x, k = threadIdx.x;
    WT[n * D + k] = (bf16)W[k * D + n];
}

// C[Mpad x 128] = A[Mpad x 128] @ W[128 x 128], bf16 in/out, no LDS.
__global__ __launch_bounds__(256) void gemm_kernel(const bf16* __restrict__ A,
                                                   const bf16* __restrict__ WT,
                                                   bf16* __restrict__ C) {
    int wave = threadIdx.x >> 6;
    int lane = threadIdx.x & 63;
    int m16  = lane & 15;
    int quad = lane >> 4;
    int row0 = blockIdx.x * 64 + wave * 16;

    bf16x8 a[4];
    const bf16* arow = A + (row0 + m16) * D + quad * 8;
#pragma unroll
    for (int kt = 0; kt < 4; ++kt)
        a[kt] = *(const bf16x8*)(arow + kt * 32);

#pragma unroll
    for (int nt = 0; nt < 8; ++nt) {
        f32x4 acc = {0.f, 0.f, 0.f, 0.f};
        const bf16* brow = WT + (nt * 16 + m16) * D + quad * 8;
#pragma unroll
        for (int kt = 0; kt < 4; ++kt) {
            bf16x8 b = *(const bf16x8*)(brow + kt * 32);
            acc = __builtin_amdgcn_mfma_f32_16x16x32_bf16(a[kt], b, acc, 0, 0, 0);
        }
#pragma unroll
        for (int r = 0; r < 4; ++r)
            C[(row0 + quad * 4 + r) * D + nt * 16 + m16] = (bf16)acc[r];
    }
}

// out[v][:] = relu( dinv[v]^2*h[v] + sum_e dinv[src]*dinv[v]*h[src] + bias )
// 4 waves/block, 1 node/wave. Within a wave: 4 edge-groups (g=lane>>4) x
// 16 lanes (c=lane&15); each lane gathers 16B (8 dims) per edge -> 16B/lane
// VMEM, zero per-edge shfls. One 16-shfl butterfly merges groups at the end.
__global__ __launch_bounds__(256) void spmm_kernel(const bf16* __restrict__ h,
                                                   const int* __restrict__ rowptr,
                                                   const int* __restrict__ csrc,
                                                   const float* __restrict__ dinv,
                                                   const float* __restrict__ bias,
                                                   bf16* __restrict__ out, int n) {
    int v = blockIdx.x * 4 + (threadIdx.x >> 6);
    if (v >= n) return;
    int lane = threadIdx.x & 63;
    int g = lane >> 4;          // edge group 0..3
    int c = lane & 15;          // dim chunk: dims c*8 .. c*8+7
    int s = rowptr[v], e = rowptr[v + 1];
    float dv = dinv[v];

    float acc[8] = {0.f, 0.f, 0.f, 0.f, 0.f, 0.f, 0.f, 0.f};

    // self-loop term (group 0 only, to count it once)
    if (g == 0) {
        uint4 u = *(const uint4*)(h + v * D + c * 8);
        float s2 = dv * dv;
        float2 f0 = bf2f(u.x), f1 = bf2f(u.y), f2 = bf2f(u.z), f3 = bf2f(u.w);
        acc[0] = s2 * f0.x; acc[1] = s2 * f0.y;
        acc[2] = s2 * f1.x; acc[3] = s2 * f1.y;
        acc[4] = s2 * f2.x; acc[5] = s2 * f2.y;
        acc[6] = s2 * f3.x; acc[7] = s2 * f3.y;
    }

    int j = s + g;
    // 2-deep unroll: edges j and j+4 (both in this group)
    for (; j + 4 < e; j += 8) {
        int s0 = csrc[j], s1 = csrc[j + 4];
        float w0 = dinv[s0] * dv, w1 = dinv[s1] * dv;
        uint4 ua = *(const uint4*)(h + s0 * D + c * 8);
        uint4 ub = *(const uint4*)(h + s1 * D + c * 8);
        float2 a0 = bf2f(ua.x), a1 = bf2f(ua.y), a2 = bf2f(ua.z), a3 = bf2f(ua.w);
        float2 b0 = bf2f(ub.x), b1 = bf2f(ub.y), b2 = bf2f(ub.z), b3 = bf2f(ub.w);
        acc[0] = fmaf(w0, a0.x, acc[0]); acc[1] = fmaf(w0, a0.y, acc[1]);
        acc[2] = fmaf(w0, a1.x, acc[2]); acc[3] = fmaf(w0, a1.y, acc[3]);
        acc[4] = fmaf(w0, a2.x, acc[4]); acc[5] = fmaf(w0, a2.y, acc[5]);
        acc[6] = fmaf(w0, a3.x, acc[6]); acc[7] = fmaf(w0, a3.y, acc[7]);
        acc[0] = fmaf(w1, b0.x, acc[0]); acc[1] = fmaf(w1, b0.y, acc[1]);
        acc[2] = fmaf(w1, b1.x, acc[2]); acc[3] = fmaf(w1, b1.y, acc[3]);
        acc[4] = fmaf(w1, b2.x, acc[4]); acc[5] = fmaf(w1, b2.y, acc[5]);
        acc[6] = fmaf(w1, b3.x, acc[6]); acc[7] = fmaf(w1, b3.y, acc[7]);
    }
    if (j < e) {
        int s0 = csrc[j];
        float w0 = dinv[s0] * dv;
        uint4 ua = *(const uint4*)(h + s0 * D + c * 8);
        float2 a0 = bf2f(ua.x), a1 = bf2f(ua.y), a2 = bf2f(ua.z), a3 = bf2f(ua.w);
        acc[0] = fmaf(w0, a0.x, acc[0]); acc[1] = fmaf(w0, a0.y, acc[1]);
        acc[2] = fmaf(w0, a1.x, acc[2]); acc[3] = fmaf(w0, a1.y, acc[3]);
        acc[4] = fmaf(w0, a2.x, acc[4]); acc[5] = fmaf(w0, a2.y, acc[5]);
        acc[6] = fmaf(w0, a3.x, acc[6]); acc[7] = fmaf(w0, a3.y, acc[7]);
    }

    // merge the 4 edge-groups (same c across g): butterfly over lane bits 4,5
#pragma unroll
    for (int d = 0; d < 8; ++d) {
        acc[d] += __shfl_xor(acc[d], 16);
        acc[d] += __shfl_xor(acc[d], 32);
    }

    if (g == 0) {
        float4 bi0 = *(const float4*)(bias + c * 8);
        float4 bi1 = *(const float4*)(bias + c * 8 + 4);
        bf16x8 o;
        o[0] = (bf16)fmaxf(acc[0] + bi0.x, 0.f);
        o[1] = (bf16)fmaxf(acc[1] + bi0.y, 0.f);
        o[2] = (bf16)fmaxf(acc[2] + bi0.z, 0.f);
        o[3] = (bf16)fmaxf(acc[3] + bi0.w, 0.f);
        o[4] = (bf16)fmaxf(acc[4] + bi1.x, 0.f);
        o[5] = (bf16)fmaxf(acc[5] + bi1.y, 0.f);
        o[6] = (bf16)fmaxf(acc[6] + bi1.z, 0.f);
        o[7] = (bf16)fmaxf(acc[7] + bi1.w, 0.f);
        *(bf16x8*)(out + v * D + c * 8) = o;
    }
}

__global__ __launch_bounds__(64) void pool_kernel(const bf16* __restrict__ h,
                                                  const int* __restrict__ starts,
                                                  float* __restrict__ pooled) {
    int g = blockIdx.x, lane = threadIdx.x;
    int s = starts[g], e = starts[g + 1];
    float ax = 0.f, ay = 0.f;
    for (int r = s; r < e; ++r) {
        unsigned u = *(const unsigned*)(h + r * D + lane * 2);
        float2 f = bf2f(u);
        ax += f.x; ay += f.y;
    }
    float c = fmaxf((float)(e - s), 1.0f);
    pooled[g * D + lane * 2]     = ax / c;
    pooled[g * D + lane * 2 + 1] = ay / c;
}

__global__ __launch_bounds__(256) void fc_kernel(const float* __restrict__ pooled,
                                                 const float* __restrict__ Wfc,
                                                 const float* __restrict__ bfc,
                                                 const float* __restrict__ Wfc2,
                                                 const float* __restrict__ bfc2,
                                                 float* __restrict__ out) {
    __shared__ float pr[D];
    __shared__ float hid[D_FF];
    int g = blockIdx.x, t = threadIdx.x;
    if (t < D) pr[t] = pooled[g * D + t];
    __syncthreads();
    float acc = bfc[t];
    for (int k = 0; k < D; ++k) acc = fmaf(pr[k], Wfc[k * D_FF + t], acc);
    hid[t] = fmaxf(acc, 0.f);
    __syncthreads();
    if (t < N_CLASSES) {
        float o = bfc2[t];
        for (int k = 0; k < D_FF; ++k) o = fmaf(hid[k], Wfc2[k * N_CLASSES + t], o);
        out[g * N_CLASSES + t] = o;
    }
}

// ---------------- launch ----------------

extern "C" void kernel_launch(void* const* d_in, const int* in_sizes, int n_in,
                              void* d_out, int out_size, void* d_ws, size_t ws_size,
                              hipStream_t stream) {
    const float* x     = (const float*)d_in[0];
    const int*   eidx  = (const int*)d_in[1];
    const int*   batch = (const int*)d_in[2];
    const float* W[3]  = { (const float*)d_in[3], (const float*)d_in[5], (const float*)d_in[7] };
    const float* b[3]  = { (const float*)d_in[4], (const float*)d_in[6], (const float*)d_in[8] };
    const float* Wfc   = (const float*)d_in[9];
    const float* bfc   = (const float*)d_in[10];
    const float* Wfc2  = (const float*)d_in[11];
    const float* bfc2  = (const float*)d_in[12];
    float* out = (float*)d_out;

    const int E = in_sizes[1] / 2;           // 3,200,000
    const int N = in_sizes[0] / D;           // 100,000
    const int* esrc = eidx;
    const int* edst = eidx + E;

    uint8_t* base = (uint8_t*)d_ws;
    size_t off = 0;
    auto alloc = [&](size_t bytes) -> void* {
        void* p = base + off;
        off = (off + bytes + 255) & ~(size_t)255;
        return p;
    };
    bf16*  hA     = (bf16*) alloc((size_t)N_PAD * D * 2);
    bf16*  hB     = (bf16*) alloc((size_t)N_PAD * D * 2);
    bf16*  Xb     = (bf16*) alloc((size_t)N_PAD * D * 2);
    bf16*  WT     = (bf16*) alloc((size_t)D * D * 2);
    int*   csrc   = (int*)  alloc((size_t)E * 4);
    int*   ebuf   = (int*)  alloc((size_t)E * 4);
    int*   gcount = (int*)  alloc((size_t)NBUCK * NB1 * 4);
    int*   gbase  = (int*)  alloc((size_t)(NBUCK * NB1 + 1) * 4);
    int*   localr = (int*)  alloc((size_t)N * 4);
    int*   rowptr = (int*)  alloc((size_t)(N + 1) * 4);
    float* dinv   = (float*)alloc((size_t)N * 4);
    int*   btotal = (int*)  alloc(1024);
    int*   bbase  = (int*)  alloc(1024);
    int*   bsum   = (int*)  alloc(4096);
    int*   boff   = (int*)  alloc(4096);
    int*   starts = (int*)  alloc((size_t)(N_GRAPHS + 1) * 4);
    float* pooled = (float*)alloc((size_t)N_GRAPHS * D * 4);
    (void)ws_size; (void)n_in; (void)out_size;

    const int NB  = (N + 255) / 256;                    // 391
    const int CB  = (N_PAD * D / 4 + 255) / 256;
    const int GB  = N_PAD / 64;                         // 1563
    const int SB  = (N + 3) / 4;                        // spmm blocks
    const int GCN = NBUCK * NB1;                        // 200704
    const int GCB = (GCN + 255) / 256;                  // 784

    // CSR build (atomic-free, LDS counting sort)
    p1_hist<<<NB1, 256, 0, stream>>>(edst, gcount, E);
    scan1<<<GCB, 256, 0, stream>>>(gcount, gbase, bsum, GCN);
    scan2<<<1, 1024, 0, stream>>>(bsum, boff, GCB);
    scan3<<<GCB, 256, 0, stream>>>(gbase, boff, GCN);
    p3_scatter<<<NB1, 256, 0, stream>>>(esrc, edst, gbase, ebuf, E);
    p4_count<<<NBUCK, 256, 0, stream>>>(ebuf, gbase, localr, dinv, btotal, E, N);
    p4b_scan<<<1, 256, 0, stream>>>(btotal, bbase, rowptr, E, N);
    p5_fill<<<NBUCK, 256, 0, stream>>>(ebuf, gbase, localr, bbase, rowptr, csrc, E, N);

    // pooling segments
    init_starts<<<3, 256, 0, stream>>>(starts);
    find_starts<<<NB, 256, 0, stream>>>(batch, starts, N);
    fix_starts<<<1, 64, 0, stream>>>(starts);

    cast4_kernel<<<CB, 256, 0, stream>>>(x, Xb, N * D, N_PAD * D);

    const bf16* layer_in = Xb;
    for (int l = 0; l < 3; ++l) {
        castWT_kernel<<<D, D, 0, stream>>>(W[l], WT);
        gemm_kernel<<<GB, 256, 0, stream>>>(layer_in, WT, hA);
        spmm_kernel<<<SB, 256, 0, stream>>>(hA, rowptr, csrc, dinv, b[l], hB, N);
        layer_in = hB;
    }

    pool_kernel<<<N_GRAPHS, 64, 0, stream>>>(hB, starts, pooled);
    fc_kernel<<<N_GRAPHS, 256, 0, stream>>>(pooled, Wfc, bfc, Wfc2, bfc2, out);
}

// Round 7
// 738.696 us; speedup vs baseline: 1.2125x; 1.0582x over previous
//
#include <hip/hip_runtime.h>
#include <hip/hip_bf16.h>

typedef __bf16 bf16;
typedef __attribute__((ext_vector_type(8))) __bf16 bf16x8;
typedef __attribute__((ext_vector_type(4))) __bf16 bf16x4;
typedef __attribute__((ext_vector_type(2))) __bf16 bf16x2;
typedef __attribute__((ext_vector_type(4))) float f32x4;

constexpr int N_NODES   = 100000;
constexpr int N_PAD     = 100032;   // multiple of 64 (GEMM block tile)
constexpr int D         = 128;
constexpr int D_FF      = 256;
constexpr int N_CLASSES = 26;
constexpr int N_GRAPHS  = 512;
constexpr int NB1       = 1024;                      // partition blocks
constexpr int NBUCK     = (N_NODES + 511) / 512;     // 196 dst-buckets of 512 nodes

__device__ inline float2 bf2f(unsigned u) {
    float lo = __uint_as_float(u << 16);
    float hi = __uint_as_float(u & 0xffff0000u);
    return make_float2(lo, hi);
}

// ---------------- CSR build: atomic-free bucket counting sort ----------------

// P1: per-block LDS histogram over dst buckets (bucket = dst >> 9)
__global__ __launch_bounds__(256) void p1_hist(const int* __restrict__ edst,
                                               int* __restrict__ gcount, int e) {
    __shared__ int cnt[NBUCK];
    for (int t = threadIdx.x; t < NBUCK; t += 256) cnt[t] = 0;
    __syncthreads();
    int chunk = (e + NB1 - 1) / NB1;
    int lo = blockIdx.x * chunk;
    int hi = min(e, lo + chunk);
    for (int i = lo + threadIdx.x; i < hi; i += 256)
        atomicAdd(&cnt[edst[i] >> 9], 1);
    __syncthreads();
    for (int t = threadIdx.x; t < NBUCK; t += 256)
        gcount[t * NB1 + blockIdx.x] = cnt[t];
}

// 3-phase exclusive scan: out[0]=0, out[i+1]=incl[i] (+ block offsets)
__global__ __launch_bounds__(256) void scan1(const int* __restrict__ in,
                                             int* out, int* bsum, int n) {
    __shared__ int sd[256];
    int i = blockIdx.x * 256 + threadIdx.x;
    int v = (i < n) ? in[i] : 0;
    sd[threadIdx.x] = v; __syncthreads();
    for (int off = 1; off < 256; off <<= 1) {
        int t = (threadIdx.x >= off) ? sd[threadIdx.x - off] : 0;
        __syncthreads();
        sd[threadIdx.x] += t;
        __syncthreads();
    }
    if (i < n) out[i + 1] = sd[threadIdx.x];
    if (threadIdx.x == 255) bsum[blockIdx.x] = sd[255];
}

__global__ __launch_bounds__(1024) void scan2(const int* __restrict__ bsum,
                                              int* boff, int nb) {
    __shared__ int sd[1024];
    int t = threadIdx.x;
    int v = (t < nb) ? bsum[t] : 0;
    sd[t] = v; __syncthreads();
    for (int off = 1; off < 1024; off <<= 1) {
        int x = (t >= off) ? sd[t - off] : 0;
        __syncthreads();
        sd[t] += x;
        __syncthreads();
    }
    if (t < nb) boff[t] = sd[t] - v;  // exclusive
}

__global__ void scan3(int* out, const int* __restrict__ boff, int n) {
    int i = blockIdx.x * 256 + threadIdx.x;
    if (i < n) out[i + 1] += boff[blockIdx.x];
    if (i == 0) out[0] = 0;
}

// P3: scatter edges into bucket-contiguous ebuf; pack (src<<9)|(dst&511)
__global__ __launch_bounds__(256) void p3_scatter(const int* __restrict__ esrc,
                                                  const int* __restrict__ edst,
                                                  const int* __restrict__ gbase,
                                                  int* __restrict__ ebuf, int e) {
    __shared__ int cur[NBUCK];
    for (int t = threadIdx.x; t < NBUCK; t += 256)
        cur[t] = gbase[t * NB1 + blockIdx.x];
    __syncthreads();
    int chunk = (e + NB1 - 1) / NB1;
    int lo = blockIdx.x * chunk;
    int hi = min(e, lo + chunk);
    for (int i = lo + threadIdx.x; i < hi; i += 256) {
        int d = edst[i], s = esrc[i];
        int pos = atomicAdd(&cur[d >> 9], 1);   // LDS atomic
        ebuf[pos] = (s << 9) | (d & 511);
    }
}

// P4: per-bucket node degree + bucket-local exclusive rowptr (LDS) + dinv
__global__ __launch_bounds__(256) void p4_count(const int* __restrict__ ebuf,
                                                const int* __restrict__ gbase,
                                                int* __restrict__ localr,
                                                float* __restrict__ dinv,
                                                int* __restrict__ btotal, int e, int n) {
    __shared__ int cnt[512];
    __shared__ int ps[256];
    int b = blockIdx.x, t = threadIdx.x;
    cnt[t] = 0; cnt[t + 256] = 0;
    __syncthreads();
    int lo = gbase[b * NB1];
    int hi = (b + 1 < NBUCK) ? gbase[(b + 1) * NB1] : e;
    for (int i = lo + t; i < hi; i += 256)
        atomicAdd(&cnt[ebuf[i] & 511], 1);      // LDS atomic
    __syncthreads();
    int a0 = cnt[t * 2], a1 = cnt[t * 2 + 1];
    ps[t] = a0 + a1;
    __syncthreads();
    for (int off = 1; off < 256; off <<= 1) {
        int v = (t >= off) ? ps[t - off] : 0;
        __syncthreads();
        ps[t] += v;
        __syncthreads();
    }
    int pexcl = (t > 0) ? ps[t - 1] : 0;
    int node0 = b * 512 + t * 2;
    if (node0 < n) {
        localr[node0] = pexcl;
        dinv[node0] = 1.0f / sqrtf((float)(a0 + 1));   // +1 self-loop
    }
    if (node0 + 1 < n) {
        localr[node0 + 1] = pexcl + a0;
        dinv[node0 + 1] = 1.0f / sqrtf((float)(a1 + 1));
    }
    if (t == 255) btotal[b] = ps[255];
}

// P4b: scan of 196 bucket totals
__global__ __launch_bounds__(256) void p4b_scan(const int* __restrict__ btotal,
                                                int* __restrict__ bbase,
                                                int* __restrict__ rowptr, int e, int n) {
    __shared__ int sd[256];
    int t = threadIdx.x;
    int v = (t < NBUCK) ? btotal[t] : 0;
    sd[t] = v; __syncthreads();
    for (int off = 1; off < 256; off <<= 1) {
        int x = (t >= off) ? sd[t - off] : 0;
        __syncthreads();
        sd[t] += x;
        __syncthreads();
    }
    if (t < NBUCK) bbase[t] = sd[t] - v;
    if (t == 0) rowptr[n] = e;
}

// P5: per-bucket CSR fill (LDS cursors; csrc writes stay in a 64KB L2 window)
__global__ __launch_bounds__(256) void p5_fill(const int* __restrict__ ebuf,
                                               const int* __restrict__ gbase,
                                               const int* __restrict__ localr,
                                               const int* __restrict__ bbase,
                                               int* __restrict__ rowptr,
                                               int* __restrict__ csrc, int e, int n) {
    __shared__ int cur[512];
    int b = blockIdx.x, t = threadIdx.x;
    int bb = bbase[b];
    for (int j = t; j < 512; j += 256) {
        int node = b * 512 + j;
        int v = 0;
        if (node < n) {
            v = bb + localr[node];
            rowptr[node] = v;
        }
        cur[j] = v;
    }
    __syncthreads();
    int lo = gbase[b * NB1];
    int hi = (b + 1 < NBUCK) ? gbase[(b + 1) * NB1] : e;
    for (int i = lo + t; i < hi; i += 256) {
        int pe = ebuf[i];
        int pos = atomicAdd(&cur[pe & 511], 1);  // LDS atomic
        csrc[pos] = pe >> 9;
    }
}

// ---------------- pooling index: starts[g] = lower_bound(batch, g) ----------------
// batch is sorted; binary search per graph (handles empty graphs + sentinel).
// Replaces the old init/find/fix_starts trio (fix_starts was a 512-long serial
// dependent-RMW chain on one thread ~= 65+ us).
__global__ __launch_bounds__(576) void starts_kernel(const int* __restrict__ batch,
                                                     int* __restrict__ starts, int n) {
    int g = threadIdx.x;
    if (g > N_GRAPHS) return;
    int lo = 0, hi = n;
    while (lo < hi) {
        int mid = (lo + hi) >> 1;
        if (batch[mid] < g) lo = mid + 1; else hi = mid;
    }
    starts[g] = lo;
}

// ---------------- dense compute ----------------

// W[l][k][n] f32 -> WT3[l][n][k] bf16, all 3 layers in one launch
__global__ void castWT3_kernel(const float* __restrict__ W0,
                               const float* __restrict__ W1,
                               const float* __restrict__ W2,
                               bf16* __restrict__ WT3) {
    int n = blockIdx.x, l = blockIdx.y, k = threadIdx.x;
    const float* W = (l == 0) ? W0 : (l == 1) ? W1 : W2;
    WT3[l * D * D + n * D + k] = (bf16)W[k * D + n];
}

// C[Mpad x 128] = A[Mpad x 128] @ W[128 x 128], bf16 in/out, no LDS.
__global__ __launch_bounds__(256) void gemm_kernel(const bf16* __restrict__ A,
                                                   const bf16* __restrict__ WT,
                                                   bf16* __restrict__ C) {
    int wave = threadIdx.x >> 6;
    int lane = threadIdx.x & 63;
    int m16  = lane & 15;
    int quad = lane >> 4;
    int row0 = blockIdx.x * 64 + wave * 16;

    bf16x8 a[4];
    const bf16* arow = A + (row0 + m16) * D + quad * 8;
#pragma unroll
    for (int kt = 0; kt < 4; ++kt)
        a[kt] = *(const bf16x8*)(arow + kt * 32);

#pragma unroll
    for (int nt = 0; nt < 8; ++nt) {
        f32x4 acc = {0.f, 0.f, 0.f, 0.f};
        const bf16* brow = WT + (nt * 16 + m16) * D + quad * 8;
#pragma unroll
        for (int kt = 0; kt < 4; ++kt) {
            bf16x8 b = *(const bf16x8*)(brow + kt * 32);
            acc = __builtin_amdgcn_mfma_f32_16x16x32_bf16(a[kt], b, acc, 0, 0, 0);
        }
#pragma unroll
        for (int r = 0; r < 4; ++r)
            C[(row0 + quad * 4 + r) * D + nt * 16 + m16] = (bf16)acc[r];
    }
}

// Layer-1 variant: A is f32 (the raw input x); cast to bf16 in-register.
// Identical numerics to cast4+gemm (same f32->bf16 rounding), one less pass.
__global__ __launch_bounds__(256) void gemm_f32_kernel(const float* __restrict__ A,
                                                       const bf16* __restrict__ WT,
                                                       bf16* __restrict__ C, int n) {
    int wave = threadIdx.x >> 6;
    int lane = threadIdx.x & 63;
    int m16  = lane & 15;
    int quad = lane >> 4;
    int row0 = blockIdx.x * 64 + wave * 16;
    int arowi = row0 + m16;

    bf16x8 a[4];
    const float* arow = A + (size_t)arowi * D + quad * 8;
#pragma unroll
    for (int kt = 0; kt < 4; ++kt) {
        float4 f0 = make_float4(0.f, 0.f, 0.f, 0.f);
        float4 f1 = make_float4(0.f, 0.f, 0.f, 0.f);
        if (arowi < n) {
            f0 = *(const float4*)(arow + kt * 32);
            f1 = *(const float4*)(arow + kt * 32 + 4);
        }
        bf16x8 v = { (bf16)f0.x, (bf16)f0.y, (bf16)f0.z, (bf16)f0.w,
                     (bf16)f1.x, (bf16)f1.y, (bf16)f1.z, (bf16)f1.w };
        a[kt] = v;
    }

#pragma unroll
    for (int nt = 0; nt < 8; ++nt) {
        f32x4 acc = {0.f, 0.f, 0.f, 0.f};
        const bf16* brow = WT + (nt * 16 + m16) * D + quad * 8;
#pragma unroll
        for (int kt = 0; kt < 4; ++kt) {
            bf16x8 b = *(const bf16x8*)(brow + kt * 32);
            acc = __builtin_amdgcn_mfma_f32_16x16x32_bf16(a[kt], b, acc, 0, 0, 0);
        }
#pragma unroll
        for (int r = 0; r < 4; ++r)
            C[(row0 + quad * 4 + r) * D + nt * 16 + m16] = (bf16)acc[r];
    }
}

// out[v][:] = relu( dinv[v]^2*h[v] + sum_e dinv[src]*dinv[v]*h[src] + bias )
// 4 waves/block, 1 node/wave. 4 edge-groups x 16 lanes; 16B/lane gathers.
// At the memory-side random-gather ceiling (R5/R6: 370MB @ 3.65TB/s) — do not touch.
__global__ __launch_bounds__(256) void spmm_kernel(const bf16* __restrict__ h,
                                                   const int* __restrict__ rowptr,
                                                   const int* __restrict__ csrc,
                                                   const float* __restrict__ dinv,
                                                   const float* __restrict__ bias,
                                                   bf16* __restrict__ out, int n) {
    int v = blockIdx.x * 4 + (threadIdx.x >> 6);
    if (v >= n) return;
    int lane = threadIdx.x & 63;
    int g = lane >> 4;          // edge group 0..3
    int c = lane & 15;          // dim chunk: dims c*8 .. c*8+7
    int s = rowptr[v], e = rowptr[v + 1];
    float dv = dinv[v];

    float acc[8] = {0.f, 0.f, 0.f, 0.f, 0.f, 0.f, 0.f, 0.f};

    if (g == 0) {
        uint4 u = *(const uint4*)(h + v * D + c * 8);
        float s2 = dv * dv;
        float2 f0 = bf2f(u.x), f1 = bf2f(u.y), f2 = bf2f(u.z), f3 = bf2f(u.w);
        acc[0] = s2 * f0.x; acc[1] = s2 * f0.y;
        acc[2] = s2 * f1.x; acc[3] = s2 * f1.y;
        acc[4] = s2 * f2.x; acc[5] = s2 * f2.y;
        acc[6] = s2 * f3.x; acc[7] = s2 * f3.y;
    }

    int j = s + g;
    for (; j + 4 < e; j += 8) {
        int s0 = csrc[j], s1 = csrc[j + 4];
        float w0 = dinv[s0] * dv, w1 = dinv[s1] * dv;
        uint4 ua = *(const uint4*)(h + s0 * D + c * 8);
        uint4 ub = *(const uint4*)(h + s1 * D + c * 8);
        float2 a0 = bf2f(ua.x), a1 = bf2f(ua.y), a2 = bf2f(ua.z), a3 = bf2f(ua.w);
        float2 b0 = bf2f(ub.x), b1 = bf2f(ub.y), b2 = bf2f(ub.z), b3 = bf2f(ub.w);
        acc[0] = fmaf(w0, a0.x, acc[0]); acc[1] = fmaf(w0, a0.y, acc[1]);
        acc[2] = fmaf(w0, a1.x, acc[2]); acc[3] = fmaf(w0, a1.y, acc[3]);
        acc[4] = fmaf(w0, a2.x, acc[4]); acc[5] = fmaf(w0, a2.y, acc[5]);
        acc[6] = fmaf(w0, a3.x, acc[6]); acc[7] = fmaf(w0, a3.y, acc[7]);
        acc[0] = fmaf(w1, b0.x, acc[0]); acc[1] = fmaf(w1, b0.y, acc[1]);
        acc[2] = fmaf(w1, b1.x, acc[2]); acc[3] = fmaf(w1, b1.y, acc[3]);
        acc[4] = fmaf(w1, b2.x, acc[4]); acc[5] = fmaf(w1, b2.y, acc[5]);
        acc[6] = fmaf(w1, b3.x, acc[6]); acc[7] = fmaf(w1, b3.y, acc[7]);
    }
    if (j < e) {
        int s0 = csrc[j];
        float w0 = dinv[s0] * dv;
        uint4 ua = *(const uint4*)(h + s0 * D + c * 8);
        float2 a0 = bf2f(ua.x), a1 = bf2f(ua.y), a2 = bf2f(ua.z), a3 = bf2f(ua.w);
        acc[0] = fmaf(w0, a0.x, acc[0]); acc[1] = fmaf(w0, a0.y, acc[1]);
        acc[2] = fmaf(w0, a1.x, acc[2]); acc[3] = fmaf(w0, a1.y, acc[3]);
        acc[4] = fmaf(w0, a2.x, acc[4]); acc[5] = fmaf(w0, a2.y, acc[5]);
        acc[6] = fmaf(w0, a3.x, acc[6]); acc[7] = fmaf(w0, a3.y, acc[7]);
    }

#pragma unroll
    for (int d = 0; d < 8; ++d) {
        acc[d] += __shfl_xor(acc[d], 16);
        acc[d] += __shfl_xor(acc[d], 32);
    }

    if (g == 0) {
        float4 bi0 = *(const float4*)(bias + c * 8);
        float4 bi1 = *(const float4*)(bias + c * 8 + 4);
        bf16x8 o;
        o[0] = (bf16)fmaxf(acc[0] + bi0.x, 0.f);
        o[1] = (bf16)fmaxf(acc[1] + bi0.y, 0.f);
        o[2] = (bf16)fmaxf(acc[2] + bi0.z, 0.f);
        o[3] = (bf16)fmaxf(acc[3] + bi0.w, 0.f);
        o[4] = (bf16)fmaxf(acc[4] + bi1.x, 0.f);
        o[5] = (bf16)fmaxf(acc[5] + bi1.y, 0.f);
        o[6] = (bf16)fmaxf(acc[6] + bi1.z, 0.f);
        o[7] = (bf16)fmaxf(acc[7] + bi1.w, 0.f);
        *(bf16x8*)(out + v * D + c * 8) = o;
    }
}

__global__ __launch_bounds__(64) void pool_kernel(const bf16* __restrict__ h,
                                                  const int* __restrict__ starts,
                                                  float* __restrict__ pooled) {
    int g = blockIdx.x, lane = threadIdx.x;
    int s = starts[g], e = starts[g + 1];
    float ax = 0.f, ay = 0.f;
    for (int r = s; r < e; ++r) {
        unsigned u = *(const unsigned*)(h + r * D + lane * 2);
        float2 f = bf2f(u);
        ax += f.x; ay += f.y;
    }
    float c = fmaxf((float)(e - s), 1.0f);
    pooled[g * D + lane * 2]     = ax / c;
    pooled[g * D + lane * 2 + 1] = ay / c;
}

__global__ __launch_bounds__(256) void fc_kernel(const float* __restrict__ pooled,
                                                 const float* __restrict__ Wfc,
                                                 const float* __restrict__ bfc,
                                                 const float* __restrict__ Wfc2,
                                                 const float* __restrict__ bfc2,
                                                 float* __restrict__ out) {
    __shared__ float pr[D];
    __shared__ float hid[D_FF];
    int g = blockIdx.x, t = threadIdx.x;
    if (t < D) pr[t] = pooled[g * D + t];
    __syncthreads();
    float acc = bfc[t];
    for (int k = 0; k < D; ++k) acc = fmaf(pr[k], Wfc[k * D_FF + t], acc);
    hid[t] = fmaxf(acc, 0.f);
    __syncthreads();
    if (t < N_CLASSES) {
        float o = bfc2[t];
        for (int k = 0; k < D_FF; ++k) o = fmaf(hid[k], Wfc2[k * N_CLASSES + t], o);
        out[g * N_CLASSES + t] = o;
    }
}

// ---------------- launch ----------------

extern "C" void kernel_launch(void* const* d_in, const int* in_sizes, int n_in,
                              void* d_out, int out_size, void* d_ws, size_t ws_size,
                              hipStream_t stream) {
    const float* x     = (const float*)d_in[0];
    const int*   eidx  = (const int*)d_in[1];
    const int*   batch = (const int*)d_in[2];
    const float* W[3]  = { (const float*)d_in[3], (const float*)d_in[5], (const float*)d_in[7] };
    const float* b[3]  = { (const float*)d_in[4], (const float*)d_in[6], (const float*)d_in[8] };
    const float* Wfc   = (const float*)d_in[9];
    const float* bfc   = (const float*)d_in[10];
    const float* Wfc2  = (const float*)d_in[11];
    const float* bfc2  = (const float*)d_in[12];
    float* out = (float*)d_out;

    const int E = in_sizes[1] / 2;           // 3,200,000
    const int N = in_sizes[0] / D;           // 100,000
    const int* esrc = eidx;
    const int* edst = eidx + E;

    uint8_t* base = (uint8_t*)d_ws;
    size_t off = 0;
    auto alloc = [&](size_t bytes) -> void* {
        void* p = base + off;
        off = (off + bytes + 255) & ~(size_t)255;
        return p;
    };
    bf16*  hA     = (bf16*) alloc((size_t)N_PAD * D * 2);
    bf16*  hB     = (bf16*) alloc((size_t)N_PAD * D * 2);
    bf16*  WT3    = (bf16*) alloc((size_t)3 * D * D * 2);
    int*   csrc   = (int*)  alloc((size_t)E * 4);
    int*   ebuf   = (int*)  alloc((size_t)E * 4);
    int*   gcount = (int*)  alloc((size_t)NBUCK * NB1 * 4);
    int*   gbase  = (int*)  alloc((size_t)(NBUCK * NB1 + 1) * 4);
    int*   localr = (int*)  alloc((size_t)N * 4);
    int*   rowptr = (int*)  alloc((size_t)(N + 1) * 4);
    float* dinv   = (float*)alloc((size_t)N * 4);
    int*   btotal = (int*)  alloc(1024);
    int*   bbase  = (int*)  alloc(1024);
    int*   bsum   = (int*)  alloc(4096);
    int*   boff   = (int*)  alloc(4096);
    int*   starts = (int*)  alloc((size_t)(N_GRAPHS + 1) * 4);
    float* pooled = (float*)alloc((size_t)N_GRAPHS * D * 4);
    (void)ws_size; (void)n_in; (void)out_size;

    const int GB  = N_PAD / 64;                         // 1563
    const int SB  = (N + 3) / 4;                        // spmm blocks
    const int GCN = NBUCK * NB1;                        // 200704
    const int GCB = (GCN + 255) / 256;                  // 784

    // CSR build (atomic-free, LDS counting sort)
    p1_hist<<<NB1, 256, 0, stream>>>(edst, gcount, E);
    scan1<<<GCB, 256, 0, stream>>>(gcount, gbase, bsum, GCN);
    scan2<<<1, 1024, 0, stream>>>(bsum, boff, GCB);
    scan3<<<GCB, 256, 0, stream>>>(gbase, boff, GCN);
    p3_scatter<<<NB1, 256, 0, stream>>>(esrc, edst, gbase, ebuf, E);
    p4_count<<<NBUCK, 256, 0, stream>>>(ebuf, gbase, localr, dinv, btotal, E, N);
    p4b_scan<<<1, 256, 0, stream>>>(btotal, bbase, rowptr, E, N);
    p5_fill<<<NBUCK, 256, 0, stream>>>(ebuf, gbase, localr, bbase, rowptr, csrc, E, N);

    // pooling segments: parallel binary search (replaces serial fix_starts)
    starts_kernel<<<1, 576, 0, stream>>>(batch, starts, N);

    // weights for all 3 layers
    castWT3_kernel<<<dim3(D, 3), D, 0, stream>>>(W[0], W[1], W[2], WT3);

    // layer 1 (f32 input, in-register cast), then layers 2-3
    gemm_f32_kernel<<<GB, 256, 0, stream>>>(x, WT3, hA, N);
    spmm_kernel<<<SB, 256, 0, stream>>>(hA, rowptr, csrc, dinv, b[0], hB, N);
    for (int l = 1; l < 3; ++l) {
        gemm_kernel<<<GB, 256, 0, stream>>>(hB, WT3 + (size_t)l * D * D, hA);
        spmm_kernel<<<SB, 256, 0, stream>>>(hA, rowptr, csrc, dinv, b[l], hB, N);
    }

    pool_kernel<<<N_GRAPHS, 64, 0, stream>>>(hB, starts, pooled);
    fc_kernel<<<N_GRAPHS, 256, 0, stream>>>(pooled, Wfc, bfc, Wfc2, bfc2, out);
}

// Round 8
// 675.229 us; speedup vs baseline: 1.3264x; 1.0940x over previous
//
#include <hip/hip_runtime.h>
#include <hip/hip_bf16.h>

typedef __bf16 bf16;
typedef __attribute__((ext_vector_type(8))) __bf16 bf16x8;
typedef __attribute__((ext_vector_type(4))) __bf16 bf16x4;
typedef __attribute__((ext_vector_type(2))) __bf16 bf16x2;
typedef __attribute__((ext_vector_type(4))) float f32x4;

constexpr int N_NODES   = 100000;
constexpr int N_PAD     = 100032;   // multiple of 64 (GEMM block tile)
constexpr int D         = 128;
constexpr int D_FF      = 256;
constexpr int N_CLASSES = 26;
constexpr int N_GRAPHS  = 512;
constexpr int NB1       = 1024;                      // partition blocks
constexpr int NBUCK     = (N_NODES + 511) / 512;     // 196 dst-buckets of 512 nodes

__device__ inline float2 bf2f(unsigned u) {
    float lo = __uint_as_float(u << 16);
    float hi = __uint_as_float(u & 0xffff0000u);
    return make_float2(lo, hi);
}

// ---------------- CSR build: atomic-free bucket counting sort ----------------

// P1: per-block LDS histogram over dst buckets (bucket = dst >> 9)
__global__ __launch_bounds__(256) void p1_hist(const int* __restrict__ edst,
                                               int* __restrict__ gcount, int e) {
    __shared__ int cnt[NBUCK];
    for (int t = threadIdx.x; t < NBUCK; t += 256) cnt[t] = 0;
    __syncthreads();
    int chunk = (e + NB1 - 1) / NB1;
    int lo = blockIdx.x * chunk;
    int hi = min(e, lo + chunk);
    for (int i = lo + threadIdx.x; i < hi; i += 256)
        atomicAdd(&cnt[edst[i] >> 9], 1);
    __syncthreads();
    for (int t = threadIdx.x; t < NBUCK; t += 256)
        gcount[t * NB1 + blockIdx.x] = cnt[t];
}

// 3-phase exclusive scan: out[0]=0, out[i+1]=incl[i] (+ block offsets)
__global__ __launch_bounds__(256) void scan1(const int* __restrict__ in,
                                             int* out, int* bsum, int n) {
    __shared__ int sd[256];
    int i = blockIdx.x * 256 + threadIdx.x;
    int v = (i < n) ? in[i] : 0;
    sd[threadIdx.x] = v; __syncthreads();
    for (int off = 1; off < 256; off <<= 1) {
        int t = (threadIdx.x >= off) ? sd[threadIdx.x - off] : 0;
        __syncthreads();
        sd[threadIdx.x] += t;
        __syncthreads();
    }
    if (i < n) out[i + 1] = sd[threadIdx.x];
    if (threadIdx.x == 255) bsum[blockIdx.x] = sd[255];
}

__global__ __launch_bounds__(1024) void scan2(const int* __restrict__ bsum,
                                              int* boff, int nb) {
    __shared__ int sd[1024];
    int t = threadIdx.x;
    int v = (t < nb) ? bsum[t] : 0;
    sd[t] = v; __syncthreads();
    for (int off = 1; off < 1024; off <<= 1) {
        int x = (t >= off) ? sd[t - off] : 0;
        __syncthreads();
        sd[t] += x;
        __syncthreads();
    }
    if (t < nb) boff[t] = sd[t] - v;  // exclusive
}

__global__ void scan3(int* out, const int* __restrict__ boff, int n) {
    int i = blockIdx.x * 256 + threadIdx.x;
    if (i < n) out[i + 1] += boff[blockIdx.x];
    if (i == 0) out[0] = 0;
}

// P3: scatter edges into bucket-contiguous ebuf; pack (src<<9)|(dst&511)
__global__ __launch_bounds__(256) void p3_scatter(const int* __restrict__ esrc,
                                                  const int* __restrict__ edst,
                                                  const int* __restrict__ gbase,
                                                  int* __restrict__ ebuf, int e) {
    __shared__ int cur[NBUCK];
    for (int t = threadIdx.x; t < NBUCK; t += 256)
        cur[t] = gbase[t * NB1 + blockIdx.x];
    __syncthreads();
    int chunk = (e + NB1 - 1) / NB1;
    int lo = blockIdx.x * chunk;
    int hi = min(e, lo + chunk);
    for (int i = lo + threadIdx.x; i < hi; i += 256) {
        int d = edst[i], s = esrc[i];
        int pos = atomicAdd(&cur[d >> 9], 1);   // LDS atomic
        ebuf[pos] = (s << 9) | (d & 511);
    }
}

// P45: fused per-bucket degree count + LDS scan + CSR fill.
// Key identity: the bucket's CSR base == its ebuf base (gbase[b*NB1]) since
// both orders are bucket-major — the old p4b bucket-total scan was redundant.
// Second ebuf pass re-reads the same ~65KB window (L2-hot: 196 blocks ~ 1/CU).
__global__ __launch_bounds__(256) void p45_fill(const int* __restrict__ ebuf,
                                                const int* __restrict__ gbase,
                                                float* __restrict__ dinv,
                                                int* __restrict__ rowptr,
                                                int* __restrict__ csrc, int e, int n) {
    __shared__ int cnt[512];
    __shared__ int ps[256];
    __shared__ int cur[512];
    int b = blockIdx.x, t = threadIdx.x;
    cnt[t] = 0; cnt[t + 256] = 0;
    __syncthreads();
    int lo = gbase[b * NB1];
    int hi = (b + 1 < NBUCK) ? gbase[(b + 1) * NB1] : e;
    for (int i = lo + t; i < hi; i += 256)
        atomicAdd(&cnt[ebuf[i] & 511], 1);      // LDS atomic
    __syncthreads();
    int a0 = cnt[t * 2], a1 = cnt[t * 2 + 1];
    ps[t] = a0 + a1;
    __syncthreads();
    for (int off = 1; off < 256; off <<= 1) {
        int v = (t >= off) ? ps[t - off] : 0;
        __syncthreads();
        ps[t] += v;
        __syncthreads();
    }
    int pexcl = (t > 0) ? ps[t - 1] : 0;
    int g0 = lo + pexcl;                 // global CSR slot of node b*512+2t
    int node0 = b * 512 + t * 2;
    cur[t * 2] = g0;
    cur[t * 2 + 1] = g0 + a0;
    if (node0 < n) {
        rowptr[node0] = g0;
        dinv[node0] = 1.0f / sqrtf((float)(a0 + 1));   // +1 self-loop
    }
    if (node0 + 1 < n) {
        rowptr[node0 + 1] = g0 + a0;
        dinv[node0 + 1] = 1.0f / sqrtf((float)(a1 + 1));
    }
    if (b == 0 && t == 0) rowptr[n] = e;
    __syncthreads();
    for (int i = lo + t; i < hi; i += 256) {
        int pe = ebuf[i];
        int pos = atomicAdd(&cur[pe & 511], 1);  // LDS atomic
        csrc[pos] = pe >> 9;
    }
}

// ---------------- pooling index: starts[g] = lower_bound(batch, g) ----------------
__global__ __launch_bounds__(576) void starts_kernel(const int* __restrict__ batch,
                                                     int* __restrict__ starts, int n) {
    int g = threadIdx.x;
    if (g > N_GRAPHS) return;
    int lo = 0, hi = n;
    while (lo < hi) {
        int mid = (lo + hi) >> 1;
        if (batch[mid] < g) lo = mid + 1; else hi = mid;
    }
    starts[g] = lo;
}

// ---------------- dense compute ----------------

// W[l][k][n] f32 -> WT3[l][n][k] bf16, all 3 layers in one launch
__global__ void castWT3_kernel(const float* __restrict__ W0,
                               const float* __restrict__ W1,
                               const float* __restrict__ W2,
                               bf16* __restrict__ WT3) {
    int n = blockIdx.x, l = blockIdx.y, k = threadIdx.x;
    const float* W = (l == 0) ? W0 : (l == 1) ? W1 : W2;
    WT3[l * D * D + n * D + k] = (bf16)W[k * D + n];
}

// C[Mpad x 128] = A[Mpad x 128] @ W[128 x 128], bf16 in/out, no LDS.
__global__ __launch_bounds__(256) void gemm_kernel(const bf16* __restrict__ A,
                                                   const bf16* __restrict__ WT,
                                                   bf16* __restrict__ C) {
    int wave = threadIdx.x >> 6;
    int lane = threadIdx.x & 63;
    int m16  = lane & 15;
    int quad = lane >> 4;
    int row0 = blockIdx.x * 64 + wave * 16;

    bf16x8 a[4];
    const bf16* arow = A + (row0 + m16) * D + quad * 8;
#pragma unroll
    for (int kt = 0; kt < 4; ++kt)
        a[kt] = *(const bf16x8*)(arow + kt * 32);

#pragma unroll
    for (int nt = 0; nt < 8; ++nt) {
        f32x4 acc = {0.f, 0.f, 0.f, 0.f};
        const bf16* brow = WT + (nt * 16 + m16) * D + quad * 8;
#pragma unroll
        for (int kt = 0; kt < 4; ++kt) {
            bf16x8 b = *(const bf16x8*)(brow + kt * 32);
            acc = __builtin_amdgcn_mfma_f32_16x16x32_bf16(a[kt], b, acc, 0, 0, 0);
        }
#pragma unroll
        for (int r = 0; r < 4; ++r)
            C[(row0 + quad * 4 + r) * D + nt * 16 + m16] = (bf16)acc[r];
    }
}

// Layer-1 variant: A is f32 (the raw input x); cast to bf16 in-register.
__global__ __launch_bounds__(256) void gemm_f32_kernel(const float* __restrict__ A,
                                                       const bf16* __restrict__ WT,
                                                       bf16* __restrict__ C, int n) {
    int wave = threadIdx.x >> 6;
    int lane = threadIdx.x & 63;
    int m16  = lane & 15;
    int quad = lane >> 4;
    int row0 = blockIdx.x * 64 + wave * 16;
    int arowi = row0 + m16;

    bf16x8 a[4];
    const float* arow = A + (size_t)arowi * D + quad * 8;
#pragma unroll
    for (int kt = 0; kt < 4; ++kt) {
        float4 f0 = make_float4(0.f, 0.f, 0.f, 0.f);
        float4 f1 = make_float4(0.f, 0.f, 0.f, 0.f);
        if (arowi < n) {
            f0 = *(const float4*)(arow + kt * 32);
            f1 = *(const float4*)(arow + kt * 32 + 4);
        }
        bf16x8 v = { (bf16)f0.x, (bf16)f0.y, (bf16)f0.z, (bf16)f0.w,
                     (bf16)f1.x, (bf16)f1.y, (bf16)f1.z, (bf16)f1.w };
        a[kt] = v;
    }

#pragma unroll
    for (int nt = 0; nt < 8; ++nt) {
        f32x4 acc = {0.f, 0.f, 0.f, 0.f};
        const bf16* brow = WT + (nt * 16 + m16) * D + quad * 8;
#pragma unroll
        for (int kt = 0; kt < 4; ++kt) {
            bf16x8 b = *(const bf16x8*)(brow + kt * 32);
            acc = __builtin_amdgcn_mfma_f32_16x16x32_bf16(a[kt], b, acc, 0, 0, 0);
        }
#pragma unroll
        for (int r = 0; r < 4; ++r)
            C[(row0 + quad * 4 + r) * D + nt * 16 + m16] = (bf16)acc[r];
    }
}

// out[v][:] = relu( dinv[v]^2*h[v] + sum_e dinv[src]*dinv[v]*h[src] + bias )
// At the memory-side random-gather ceiling (R5-R7: 370MB @ 3.65TB/s) — frozen.
__global__ __launch_bounds__(256) void spmm_kernel(const bf16* __restrict__ h,
                                                   const int* __restrict__ rowptr,
                                                   const int* __restrict__ csrc,
                                                   const float* __restrict__ dinv,
                                                   const float* __restrict__ bias,
                                                   bf16* __restrict__ out, int n) {
    int v = blockIdx.x * 4 + (threadIdx.x >> 6);
    if (v >= n) return;
    int lane = threadIdx.x & 63;
    int g = lane >> 4;          // edge group 0..3
    int c = lane & 15;          // dim chunk: dims c*8 .. c*8+7
    int s = rowptr[v], e = rowptr[v + 1];
    float dv = dinv[v];

    float acc[8] = {0.f, 0.f, 0.f, 0.f, 0.f, 0.f, 0.f, 0.f};

    if (g == 0) {
        uint4 u = *(const uint4*)(h + v * D + c * 8);
        float s2 = dv * dv;
        float2 f0 = bf2f(u.x), f1 = bf2f(u.y), f2 = bf2f(u.z), f3 = bf2f(u.w);
        acc[0] = s2 * f0.x; acc[1] = s2 * f0.y;
        acc[2] = s2 * f1.x; acc[3] = s2 * f1.y;
        acc[4] = s2 * f2.x; acc[5] = s2 * f2.y;
        acc[6] = s2 * f3.x; acc[7] = s2 * f3.y;
    }

    int j = s + g;
    for (; j + 4 < e; j += 8) {
        int s0 = csrc[j], s1 = csrc[j + 4];
        float w0 = dinv[s0] * dv, w1 = dinv[s1] * dv;
        uint4 ua = *(const uint4*)(h + s0 * D + c * 8);
        uint4 ub = *(const uint4*)(h + s1 * D + c * 8);
        float2 a0 = bf2f(ua.x), a1 = bf2f(ua.y), a2 = bf2f(ua.z), a3 = bf2f(ua.w);
        float2 b0 = bf2f(ub.x), b1 = bf2f(ub.y), b2 = bf2f(ub.z), b3 = bf2f(ub.w);
        acc[0] = fmaf(w0, a0.x, acc[0]); acc[1] = fmaf(w0, a0.y, acc[1]);
        acc[2] = fmaf(w0, a1.x, acc[2]); acc[3] = fmaf(w0, a1.y, acc[3]);
        acc[4] = fmaf(w0, a2.x, acc[4]); acc[5] = fmaf(w0, a2.y, acc[5]);
        acc[6] = fmaf(w0, a3.x, acc[6]); acc[7] = fmaf(w0, a3.y, acc[7]);
        acc[0] = fmaf(w1, b0.x, acc[0]); acc[1] = fmaf(w1, b0.y, acc[1]);
        acc[2] = fmaf(w1, b1.x, acc[2]); acc[3] = fmaf(w1, b1.y, acc[3]);
        acc[4] = fmaf(w1, b2.x, acc[4]); acc[5] = fmaf(w1, b2.y, acc[5]);
        acc[6] = fmaf(w1, b3.x, acc[6]); acc[7] = fmaf(w1, b3.y, acc[7]);
    }
    if (j < e) {
        int s0 = csrc[j];
        float w0 = dinv[s0] * dv;
        uint4 ua = *(const uint4*)(h + s0 * D + c * 8);
        float2 a0 = bf2f(ua.x), a1 = bf2f(ua.y), a2 = bf2f(ua.z), a3 = bf2f(ua.w);
        acc[0] = fmaf(w0, a0.x, acc[0]); acc[1] = fmaf(w0, a0.y, acc[1]);
        acc[2] = fmaf(w0, a1.x, acc[2]); acc[3] = fmaf(w0, a1.y, acc[3]);
        acc[4] = fmaf(w0, a2.x, acc[4]); acc[5] = fmaf(w0, a2.y, acc[5]);
        acc[6] = fmaf(w0, a3.x, acc[6]); acc[7] = fmaf(w0, a3.y, acc[7]);
    }

#pragma unroll
    for (int d = 0; d < 8; ++d) {
        acc[d] += __shfl_xor(acc[d], 16);
        acc[d] += __shfl_xor(acc[d], 32);
    }

    if (g == 0) {
        float4 bi0 = *(const float4*)(bias + c * 8);
        float4 bi1 = *(const float4*)(bias + c * 8 + 4);
        bf16x8 o;
        o[0] = (bf16)fmaxf(acc[0] + bi0.x, 0.f);
        o[1] = (bf16)fmaxf(acc[1] + bi0.y, 0.f);
        o[2] = (bf16)fmaxf(acc[2] + bi0.z, 0.f);
        o[3] = (bf16)fmaxf(acc[3] + bi0.w, 0.f);
        o[4] = (bf16)fmaxf(acc[4] + bi1.x, 0.f);
        o[5] = (bf16)fmaxf(acc[5] + bi1.y, 0.f);
        o[6] = (bf16)fmaxf(acc[6] + bi1.z, 0.f);
        o[7] = (bf16)fmaxf(acc[7] + bi1.w, 0.f);
        *(bf16x8*)(out + v * D + c * 8) = o;
    }
}

// 4 waves/graph: wave w sums rows s+w, s+w+4, ...; LDS merge.
__global__ __launch_bounds__(256) void pool_kernel(const bf16* __restrict__ h,
                                                   const int* __restrict__ starts,
                                                   float* __restrict__ pooled) {
    __shared__ float part[3][D];
    int g = blockIdx.x;
    int w = threadIdx.x >> 6, lane = threadIdx.x & 63;
    int s = starts[g], e = starts[g + 1];
    float ax = 0.f, ay = 0.f;
    for (int r = s + w; r < e; r += 4) {
        unsigned u = *(const unsigned*)(h + r * D + lane * 2);
        float2 f = bf2f(u);
        ax += f.x; ay += f.y;
    }
    if (w > 0) { part[w - 1][lane * 2] = ax; part[w - 1][lane * 2 + 1] = ay; }
    __syncthreads();
    if (w == 0) {
#pragma unroll
        for (int k = 0; k < 3; ++k) { ax += part[k][lane * 2]; ay += part[k][lane * 2 + 1]; }
        float c = fmaxf((float)(e - s), 1.0f);
        pooled[g * D + lane * 2]     = ax / c;
        pooled[g * D + lane * 2 + 1] = ay / c;
    }
}

__global__ __launch_bounds__(256) void fc_kernel(const float* __restrict__ pooled,
                                                 const float* __restrict__ Wfc,
                                                 const float* __restrict__ bfc,
                                                 const float* __restrict__ Wfc2,
                                                 const float* __restrict__ bfc2,
                                                 float* __restrict__ out) {
    __shared__ float pr[D];
    __shared__ float hid[D_FF];
    int g = blockIdx.x, t = threadIdx.x;
    if (t < D) pr[t] = pooled[g * D + t];
    __syncthreads();
    float acc = bfc[t];
    for (int k = 0; k < D; ++k) acc = fmaf(pr[k], Wfc[k * D_FF + t], acc);
    hid[t] = fmaxf(acc, 0.f);
    __syncthreads();
    if (t < N_CLASSES) {
        float o = bfc2[t];
        for (int k = 0; k < D_FF; ++k) o = fmaf(hid[k], Wfc2[k * N_CLASSES + t], o);
        out[g * N_CLASSES + t] = o;
    }
}

// ---------------- launch ----------------

extern "C" void kernel_launch(void* const* d_in, const int* in_sizes, int n_in,
                              void* d_out, int out_size, void* d_ws, size_t ws_size,
                              hipStream_t stream) {
    const float* x     = (const float*)d_in[0];
    const int*   eidx  = (const int*)d_in[1];
    const int*   batch = (const int*)d_in[2];
    const float* W[3]  = { (const float*)d_in[3], (const float*)d_in[5], (const float*)d_in[7] };
    const float* b[3]  = { (const float*)d_in[4], (const float*)d_in[6], (const float*)d_in[8] };
    const float* Wfc   = (const float*)d_in[9];
    const float* bfc   = (const float*)d_in[10];
    const float* Wfc2  = (const float*)d_in[11];
    const float* bfc2  = (const float*)d_in[12];
    float* out = (float*)d_out;

    const int E = in_sizes[1] / 2;           // 3,200,000
    const int N = in_sizes[0] / D;           // 100,000
    const int* esrc = eidx;
    const int* edst = eidx + E;

    uint8_t* base = (uint8_t*)d_ws;
    size_t off = 0;
    auto alloc = [&](size_t bytes) -> void* {
        void* p = base + off;
        off = (off + bytes + 255) & ~(size_t)255;
        return p;
    };
    bf16*  hA     = (bf16*) alloc((size_t)N_PAD * D * 2);
    bf16*  hB     = (bf16*) alloc((size_t)N_PAD * D * 2);
    bf16*  WT3    = (bf16*) alloc((size_t)3 * D * D * 2);
    int*   csrc   = (int*)  alloc((size_t)E * 4);
    int*   ebuf   = (int*)  alloc((size_t)E * 4);
    int*   gcount = (int*)  alloc((size_t)NBUCK * NB1 * 4);
    int*   gbase  = (int*)  alloc((size_t)(NBUCK * NB1 + 1) * 4);
    int*   rowptr = (int*)  alloc((size_t)(N + 1) * 4);
    float* dinv   = (float*)alloc((size_t)N * 4);
    int*   bsum   = (int*)  alloc(4096);
    int*   boff   = (int*)  alloc(4096);
    int*   starts = (int*)  alloc((size_t)(N_GRAPHS + 1) * 4);
    float* pooled = (float*)alloc((size_t)N_GRAPHS * D * 4);
    (void)ws_size; (void)n_in; (void)out_size;

    const int GB  = N_PAD / 64;                         // 1563
    const int SB  = (N + 3) / 4;                        // spmm blocks
    const int GCN = NBUCK * NB1;                        // 200704
    const int GCB = (GCN + 255) / 256;                  // 784

    // CSR build (atomic-free, LDS counting sort)
    p1_hist<<<NB1, 256, 0, stream>>>(edst, gcount, E);
    scan1<<<GCB, 256, 0, stream>>>(gcount, gbase, bsum, GCN);
    scan2<<<1, 1024, 0, stream>>>(bsum, boff, GCB);
    scan3<<<GCB, 256, 0, stream>>>(gbase, boff, GCN);
    p3_scatter<<<NB1, 256, 0, stream>>>(esrc, edst, gbase, ebuf, E);
    p45_fill<<<NBUCK, 256, 0, stream>>>(ebuf, gbase, dinv, rowptr, csrc, E, N);

    // pooling segments: parallel binary search
    starts_kernel<<<1, 576, 0, stream>>>(batch, starts, N);

    // weights for all 3 layers
    castWT3_kernel<<<dim3(D, 3), D, 0, stream>>>(W[0], W[1], W[2], WT3);

    // layer 1 (f32 input, in-register cast), then layers 2-3
    gemm_f32_kernel<<<GB, 256, 0, stream>>>(x, WT3, hA, N);
    spmm_kernel<<<SB, 256, 0, stream>>>(hA, rowptr, csrc, dinv, b[0], hB, N);
    for (int l = 1; l < 3; ++l) {
        gemm_kernel<<<GB, 256, 0, stream>>>(hB, WT3 + (size_t)l * D * D, hA);
        spmm_kernel<<<SB, 256, 0, stream>>>(hA, rowptr, csrc, dinv, b[l], hB, N);
    }

    pool_kernel<<<N_GRAPHS, 256, 0, stream>>>(hB, starts, pooled);
    fc_kernel<<<N_GRAPHS, 256, 0, stream>>>(pooled, Wfc, bfc, Wfc2, bfc2, out);
}